// Round 6
// baseline (118.644 us; speedup 1.0000x reference)
//
#include <hip/hip_runtime.h>
#include <math.h>

#define NN 8192
#define HH 30
#define TPB 512
#define NIV 31      // coarse intervals (fallback)
#define TSTR 68     // fallback table row stride (floats)

__launch_bounds__(TPB, 2)
__global__ void pointnet_pwl5_kernel(
    const float* __restrict__ x,
    const float* __restrict__ W1,  const float* __restrict__ b1,
    const float* __restrict__ W2,  const float* __restrict__ b2,
    const float* __restrict__ Wa1, const float* __restrict__ ba1,
    const float* __restrict__ Wa2, const float* __restrict__ ba2,
    const float* __restrict__ Wf1, const float* __restrict__ bf1,
    const float* __restrict__ Wf2, const float* __restrict__ bf2,
    const float* __restrict__ Wf3, const float* __restrict__ bf3,
    float* __restrict__ out)
{
    // raw weights
    __shared__ float W2s[HH][32];
    __shared__ float Wa1s[HH][32];
    __shared__ float w1s[HH], b1s[HH], b2s[32], ba1s[32];
    __shared__ __align__(16) float ts_s[32];   // sorted breakpoints, INF pads
    __shared__ __align__(16) float Wa2s[32];
    __shared__ float tts[HH];
    __shared__ int   rnk[HH];
    __shared__ int   DcS, rmap1S;
    __shared__ float d0S;
    // P = W2 * Wa1 (30x32) and vb2[m] = sum_k Wa1[k][m]*b2[k]
    __shared__ float P[HH][32];
    __shared__ float vb2[32];
    // fast path (Dc==1): 2-interval tables
    __shared__ __align__(16) float ab2[2][64];   // [a0..a31 | b0..b31]
    __shared__ __align__(16) float uv2[2][64];   // [u0..u31 | v0..v31]
    __shared__ float zz_raw[128], zz_s[128];     // refined logit breakpoints
    __shared__ float2 gcs[129];                  // l(x) = g*x + c per refined interval
    // fallback coarse tables
    __shared__ __align__(16) float abt[NIV][TSTR];
    __shared__ __align__(16) float uvt[NIV][TSTR];
    // reductions / epilogue
    __shared__ float red[8][154];
    __shared__ float fin[16];
    __shared__ float feat[192];
    __shared__ float redh[12][40];
    __shared__ float z1s[40], z2s[40];
    __shared__ float wf2s[40 * 40];
    __shared__ float wf3s[40 * 5];

    const int tid = threadIdx.x;
    const int b   = blockIdx.x;

    // ---- issue ALL long-latency global loads first: latency hides under preamble ----
    float2 xl[8];
    {
        const float2* xb2 = reinterpret_cast<const float2*>(x + (size_t)b * NN);
        #pragma unroll
        for (int it = 0; it < 8; ++it) xl[it] = xb2[it * TPB + tid];
    }
    float wf1r[15];
    if (tid < 480) {
        int o = tid % 40, p = tid / 40;
        const float* wrow = Wf1 + (p * 15) * 40 + o;
        #pragma unroll
        for (int ii = 0; ii < 15; ++ii) wf1r[ii] = wrow[ii * 40];
    }
    float bf1r = 0.f, bf2r = 0.f, bf3r = 0.f;
    if (tid < 40) { bf1r = bf1[tid]; bf2r = bf2[tid]; }
    if (tid < 5)  { bf3r = bf3[tid]; }

    // ---------------- Phase A: stage raw weights + breakpoints ----------------
    for (int i = tid; i < HH * 32; i += TPB) {
        int j = i >> 5, k = i & 31;
        W2s[j][k] = (k < HH) ? W2[j * HH + k] : 0.f;
    }
    for (int i = tid; i < HH * 32; i += TPB) ((float*)Wa1s)[i] = Wa1[i];
    if (tid < HH) {
        float w = W1[tid], bb = b1[tid];
        w1s[tid] = w; b1s[tid] = bb;
        tts[tid] = (w != 0.f) ? (-bb / w) : INFINITY;
    }
    if (tid < 32) {
        b2s[tid]  = (tid < HH) ? b2[tid] : 0.f;
        ba1s[tid] = ba1[tid];
        Wa2s[tid] = Wa2[tid];
        ts_s[tid] = INFINITY;
    }
    for (int i = tid; i < 40 * 40; i += TPB) wf2s[i] = Wf2[i];
    for (int i = tid; i < 40 * 5;  i += TPB) wf3s[i] = Wf3[i];
    const float ba2v = ba2[0];
    __syncthreads();

    // ---------------- Phase B: rank sort (tid<30)  ||  P, vb2 (tid>=32) ----------------
    if (tid < HH) {
        float t = tts[tid];
        int r = 0;
        for (int i = 0; i < HH; ++i) {
            float ti = tts[i];
            r += (ti < t) || (ti == t && i < tid);
        }
        ts_s[r] = t;
        rnk[tid] = r;
    } else if (tid >= 32) {
        for (int e = tid - 32; e < HH * 32 + 32; e += (TPB - 32)) {
            if (e < HH * 32) {
                int j = e >> 5, m = e & 31;
                float s = 0.f;
                for (int k = 0; k < HH; ++k) s = fmaf(W2s[j][k], Wa1s[k][m], s);
                P[j][m] = s;
            } else {
                int m = e - HH * 32;
                float s = 0.f;
                for (int k = 0; k < HH; ++k) s = fmaf(Wa1s[k][m], b2s[k], s);
                vb2[m] = s;
            }
        }
    }
    __syncthreads();

    // ---------------- Phase C: distinct count via ballot (wave 0) ----------------
    if (tid < 64) {
        bool fin_t = (tid < HH) && (ts_s[tid] < INFINITY);
        bool neq = fin_t && (tid == 0 || ts_s[tid] != ts_s[tid - 1]);
        unsigned long long md = __ballot(neq);
        float t0v = ts_s[0];
        bool eq0 = fin_t && (ts_s[tid] == t0v);
        unsigned long long me = __ballot(eq0);
        if (tid == 0) {
            DcS = __popcll(md);
            d0S = t0v;
            int c2 = __popcll(me);
            rmap1S = (c2 > 30) ? 30 : c2;
        }
    }
    __syncthreads();
    const int Dc = DcS;

    if (Dc == 1) {
        // ================= FAST PATH: single breakpoint d0, 2 intervals =================
        const float d0 = d0S;
        const int rmap1 = rmap1S;

        // ---- Phase D (fused): ab2 (tid<64) || uv2 + zz zeros (tid 64..127) || pads ----
        if (tid < 64) {
            int r = tid >> 5, k = tid & 31;
            int rr = r ? rmap1 : 0;
            float a = 0.f, bb = 0.f;
            if (k < HH) {
                for (int j = 0; j < HH; ++j) {
                    float w = w1s[j];
                    bool act = (w > 0.f) ? (rnk[j] < rr)
                             : ((w < 0.f) ? (rnk[j] >= rr) : (b1s[j] > 0.f));
                    if (act) {
                        float w2 = W2s[j][k];
                        a  = fmaf(w,      w2, a);
                        bb = fmaf(b1s[j], w2, bb);
                    }
                }
                bb += b2s[k];
            }
            ab2[r][k]      = a;
            ab2[r][32 + k] = bb;
        } else if (tid < 128) {
            int i2 = tid - 64;
            int r = i2 >> 5, m = i2 & 31;
            int rr = r ? rmap1 : 0;
            float u = 0.f, v = 0.f;
            for (int j = 0; j < HH; ++j) {
                float w = w1s[j];
                bool act = (w > 0.f) ? (rnk[j] < rr)
                         : ((w < 0.f) ? (rnk[j] >= rr) : (b1s[j] > 0.f));
                if (act) {
                    float pj = P[j][m];
                    u = fmaf(w,      pj, u);
                    v = fmaf(b1s[j], pj, v);
                }
            }
            v += vb2[m] + ba1s[m];
            uv2[r][m]      = u;
            uv2[r][32 + m] = v;
            // zero of this preact, valid only inside its interval
            float zr = -v / u;
            bool ok = (u != 0.f) && (r == 0 ? (zr < d0) : (zr > d0));
            zz_raw[1 + i2] = ok ? zr : INFINITY;
        } else if (tid < 191) {
            zz_raw[tid - 63] = INFINITY;   // pads 65..127
        } else if (tid == 191) {
            zz_raw[0] = d0;
        }
        __syncthreads();

        // ---- Phase E: stable rank sort of 128 refined breakpoints ----
        if (tid < 128) {
            float v = zz_raw[tid];
            int rk = 0;
            for (int i = 0; i < 128; ++i) {
                float vi = zz_raw[i];
                rk += (vi < v) || (vi == v && i < tid);
            }
            zz_s[rk] = v;
        }
        __syncthreads();

        // ---- Phase F: (g,c) per refined interval via interior test point ----
        if (tid < 129) {
            float lo = (tid == 0)   ? -INFINITY : zz_s[tid - 1];
            float hi = (tid == 128) ?  INFINITY : zz_s[tid];
            float xm;
            if (lo == -INFINITY)      xm = (hi < INFINITY) ? hi - 1.f : 0.f;
            else if (hi == INFINITY)  xm = lo + 1.f;
            else                      xm = 0.5f * (lo + hi);
            int r = (xm >= d0) ? 1 : 0;
            float g = 0.f, c = ba2v;
            for (int m = 0; m < 32; ++m) {
                float u = uv2[r][m], v = uv2[r][32 + m];
                if (fmaf(u, xm, v) > 0.f) {
                    float w = Wa2s[m];
                    g = fmaf(w, u, g);
                    c = fmaf(w, v, c);
                }
            }
            gcs[tid] = make_float2(g, c);
        }
        __syncthreads();

        // ---- main loop: pure VALU on prefetched registers ----
        float c0=0,c1=0, Sx0=0,Sx1=0, Q0=0,Q1=0;
        float mn0=INFINITY,mn1=INFINITY, mx0=-INFINITY,mx1=-INFINITY;
        float Sp0=0,Sp1=0, Px0=0,Px1=0;
        float mrun = -INFINITY;

        #pragma unroll
        for (int it = 0; it < 8; ++it) {
            float xv2[2] = { xl[it].x, xl[it].y };
            #pragma unroll
            for (int pp = 0; pp < 2; ++pp) {
                float xv = xv2[pp];
                bool q1 = (xv >= d0);
                // 7-step branchless search: idx = #{zz_s <= xv}
                int idx = 0;
                #pragma unroll
                for (int bit = 64; bit >= 1; bit >>= 1) {
                    int t = idx + bit;
                    idx = (zz_s[t - 1] <= xv) ? t : idx;
                }
                float2 gc = gcs[idx];
                float l = fmaf(xv, gc.x, gc.y);
                float dlt = l - mrun, p;
                if (dlt > 8.f) {                 // rare; also first point (mrun=-INF)
                    float sc = __expf(-dlt);
                    Sp0 *= sc; Sp1 *= sc; Px0 *= sc; Px1 *= sc;
                    mrun = l; p = 1.f;
                } else p = __expf(dlt);
                float xx = xv * xv, px = p * xv;
                float i1 = q1 ? 1.f : 0.f, i0 = 1.f - i1;
                c0 += i0;                    c1 += i1;
                Sx0 = fmaf(i0, xv, Sx0);     Sx1 = fmaf(i1, xv, Sx1);
                Q0  = fmaf(i0, xx, Q0);      Q1  = fmaf(i1, xx, Q1);
                Sp0 = fmaf(i0, p,  Sp0);     Sp1 = fmaf(i1, p,  Sp1);
                Px0 = fmaf(i0, px, Px0);     Px1 = fmaf(i1, px, Px1);
                mn0 = fminf(mn0, q1 ?  INFINITY : xv);
                mx0 = fmaxf(mx0, q1 ? -INFINITY : xv);
                mn1 = fminf(mn1, q1 ? xv :  INFINITY);
                mx1 = fmaxf(mx1, q1 ? xv : -INFINITY);
            }
        }

        // ---- wave butterfly (15 quantities) ----
        #pragma unroll 1
        for (int off = 32; off > 0; off >>= 1) {
            c0  += __shfl_xor(c0,  off);  c1  += __shfl_xor(c1,  off);
            Sx0 += __shfl_xor(Sx0, off);  Sx1 += __shfl_xor(Sx1, off);
            Q0  += __shfl_xor(Q0,  off);  Q1  += __shfl_xor(Q1,  off);
            mn0 = fminf(mn0, __shfl_xor(mn0, off));
            mn1 = fminf(mn1, __shfl_xor(mn1, off));
            mx0 = fmaxf(mx0, __shfl_xor(mx0, off));
            mx1 = fmaxf(mx1, __shfl_xor(mx1, off));
            float mo = __shfl_xor(mrun, off);
            float M  = fmaxf(mrun, mo);
            float sa = __expf(mrun - M), sb = __expf(mo - M);
            float t;
            t = __shfl_xor(Sp0, off); Sp0 = Sp0 * sa + t * sb;
            t = __shfl_xor(Sp1, off); Sp1 = Sp1 * sa + t * sb;
            t = __shfl_xor(Px0, off); Px0 = Px0 * sa + t * sb;
            t = __shfl_xor(Px1, off); Px1 = Px1 * sa + t * sb;
            mrun = M;
        }

        const int wave = tid >> 6, lane = tid & 63;
        if (lane == 0) {
            float* rw = red[wave];
            rw[0]=c0; rw[1]=Sx0; rw[2]=Q0; rw[3]=mn0; rw[4]=mx0; rw[5]=Sp0; rw[6]=Px0;
            rw[7]=c1; rw[8]=Sx1; rw[9]=Q1; rw[10]=mn1; rw[11]=mx1; rw[12]=Sp1; rw[13]=Px1;
            rw[14]=mrun;
        }
        __syncthreads();

        if (tid < 2) {
            float M = red[0][14];
            #pragma unroll
            for (int w = 1; w < 8; ++w) M = fmaxf(M, red[w][14]);
            int base = tid * 7;
            float ck=0, Sx=0, Q=0, mnv=INFINITY, mxv=-INFINITY, Sp=0, Px=0;
            #pragma unroll
            for (int w = 0; w < 8; ++w) {
                ck += red[w][base+0]; Sx += red[w][base+1]; Q += red[w][base+2];
                mnv = fminf(mnv, red[w][base+3]); mxv = fmaxf(mxv, red[w][base+4]);
                float e = __expf(red[w][14] - M);
                Sp = fmaf(red[w][base+5], e, Sp);
                Px = fmaf(red[w][base+6], e, Px);
            }
            fin[base+0]=ck; fin[base+1]=Sx; fin[base+2]=Q;
            fin[base+3]=mnv; fin[base+4]=mxv; fin[base+5]=Sp; fin[base+6]=Px;
        }
        __syncthreads();

        if (tid < HH) {
            float sumk=0, ssqk=0, acck=0, L=0;
            float mxk=-INFINITY, mnk=INFINITY;
            #pragma unroll
            for (int r2 = 0; r2 < 2; ++r2) {
                float ck = fin[r2*7+0], Sx = fin[r2*7+1], Q = fin[r2*7+2];
                float xmn = fin[r2*7+3], xmx = fin[r2*7+4];
                float Sp = fin[r2*7+5], Px = fin[r2*7+6];
                float a = ab2[r2][tid], bb = ab2[r2][32 + tid];
                sumk += a * Sx + bb * ck;
                ssqk += a * a * Q + 2.f * a * bb * Sx + bb * bb * ck;
                acck += a * Px + bb * Sp;
                L += Sp;
                if (ck > 0.f) {
                    float h1 = fmaf(a, xmn, bb), h2v = fmaf(a, xmx, bb);
                    mxk = fmaxf(mxk, fmaxf(h1, h2v));
                    mnk = fminf(mnk, fminf(h1, h2v));
                }
            }
            const float invN = 1.f / (float)NN;
            float mean = sumk * invN;
            float var  = fmaxf(ssqk * invN - mean * mean, 0.f);
            feat[tid]        = mean;
            feat[30 + tid]   = mxk;
            feat[60 + tid]   = mnk;
            feat[90 + tid]   = sqrtf(var);
            feat[120 + tid]  = sumk;
            feat[150 + tid]  = acck / L;
        }
    } else {
        // ================= FALLBACK: general coarse-table per-point path =================
        for (int idx = tid; idx < NIV * 32; idx += TPB) {
            int r = idx >> 5, k = idx & 31;
            float a = 0.f, bb = 0.f;
            if (k < HH) {
                for (int j = 0; j < HH; ++j) {
                    float w = w1s[j];
                    bool act = (w > 0.f) ? (rnk[j] < r)
                             : ((w < 0.f) ? (rnk[j] >= r) : (b1s[j] > 0.f));
                    if (act) {
                        float w2 = W2s[j][k];
                        a  = fmaf(w,      w2, a);
                        bb = fmaf(b1s[j], w2, bb);
                    }
                }
                bb += b2s[k];
            }
            abt[r][k]      = a;
            abt[r][32 + k] = bb;
        }
        __syncthreads();
        for (int idx = tid; idx < NIV * 32; idx += TPB) {
            int r = idx >> 5, m = idx & 31;
            float u = 0.f, v = 0.f;
            for (int k = 0; k < HH; ++k) {
                float wa = Wa1s[k][m];
                u = fmaf(wa, abt[r][k],      u);
                v = fmaf(wa, abt[r][32 + k], v);
            }
            v += ba1s[m];
            uvt[r][m]      = u;
            uvt[r][32 + m] = v;
        }
        __syncthreads();

        float sum[HH], ssq[HH], mx[HH], mn[HH], acc[HH];
        #pragma unroll
        for (int k = 0; k < HH; ++k) {
            sum[k] = 0.f; ssq[k] = 0.f; acc[k] = 0.f;
            mx[k] = -INFINITY; mn[k] = INFINITY;
        }
        float mrun = -INFINITY, lrun = 0.f;
        const float* xb = x + (size_t)b * NN;
        const float4* ts4 = (const float4*)ts_s;
        const float4* wv4 = (const float4*)Wa2s;

        #pragma unroll 1
        for (int it = 0; it < NN / TPB; ++it) {
            float xv = xb[it * TPB + tid];
            int r = 0;
            #pragma unroll
            for (int i = 0; i < 8; ++i) {
                float4 t = ts4[i];
                r += (xv >= t.x) ? 1 : 0;
                r += (xv >= t.y) ? 1 : 0;
                r += (xv >= t.z) ? 1 : 0;
                r += (xv >= t.w) ? 1 : 0;
            }
            float h2[HH];
            const float4* arow = (const float4*)(&abt[r][0]);
            #pragma unroll
            for (int i = 0; i < 7; ++i) {
                float4 av = arow[i], bv = arow[8 + i];
                h2[4*i+0] = fmaf(xv, av.x, bv.x);
                h2[4*i+1] = fmaf(xv, av.y, bv.y);
                h2[4*i+2] = fmaf(xv, av.z, bv.z);
                h2[4*i+3] = fmaf(xv, av.w, bv.w);
            }
            { float4 av = arow[7], bv = arow[15];
              h2[28] = fmaf(xv, av.x, bv.x);
              h2[29] = fmaf(xv, av.y, bv.y); }
            #pragma unroll
            for (int k = 0; k < HH; ++k) {
                float h = h2[k];
                sum[k] += h;
                ssq[k] = fmaf(h, h, ssq[k]);
                mx[k] = fmaxf(mx[k], h);
                mn[k] = fminf(mn[k], h);
            }
            float l = ba2v;
            const float4* urow = (const float4*)(&uvt[r][0]);
            #pragma unroll
            for (int i = 0; i < 8; ++i) {
                float4 uu = urow[i], vv = urow[8 + i], ww = wv4[i];
                l = fmaf(fmaxf(fmaf(xv, uu.x, vv.x), 0.f), ww.x, l);
                l = fmaf(fmaxf(fmaf(xv, uu.y, vv.y), 0.f), ww.y, l);
                l = fmaf(fmaxf(fmaf(xv, uu.z, vv.z), 0.f), ww.z, l);
                l = fmaf(fmaxf(fmaf(xv, uu.w, vv.w), 0.f), ww.w, l);
            }
            float d = l - mrun, p;
            if (d > 8.f) {
                float s = __expf(-d);
                lrun *= s;
                #pragma unroll
                for (int k = 0; k < HH; ++k) acc[k] *= s;
                mrun = l; p = 1.f;
            } else p = __expf(d);
            lrun += p;
            #pragma unroll
            for (int k = 0; k < HH; ++k) acc[k] = fmaf(p, h2[k], acc[k]);
        }

        #pragma unroll 1
        for (int off = 32; off > 0; off >>= 1) {
            #pragma unroll
            for (int k = 0; k < HH; ++k) {
                sum[k] += __shfl_xor(sum[k], off);
                ssq[k] += __shfl_xor(ssq[k], off);
                mx[k] = fmaxf(mx[k], __shfl_xor(mx[k], off));
                mn[k] = fminf(mn[k], __shfl_xor(mn[k], off));
            }
            float mo = __shfl_xor(mrun, off);
            float lo = __shfl_xor(lrun, off);
            float M  = fmaxf(mrun, mo);
            float sa = __expf(mrun - M), sb = __expf(mo - M);
            lrun = lrun * sa + lo * sb;
            #pragma unroll
            for (int k = 0; k < HH; ++k)
                acc[k] = acc[k] * sa + __shfl_xor(acc[k], off) * sb;
            mrun = M;
        }

        const int wave = tid >> 6, lane = tid & 63;
        if (lane == 0) {
            #pragma unroll
            for (int k = 0; k < HH; ++k) {
                red[wave][k]       = sum[k];
                red[wave][30 + k]  = ssq[k];
                red[wave][60 + k]  = mx[k];
                red[wave][90 + k]  = mn[k];
                red[wave][120 + k] = acc[k];
            }
            red[wave][150] = mrun;
            red[wave][151] = lrun;
        }
        __syncthreads();

        if (tid < HH) {
            float M = -INFINITY;
            #pragma unroll
            for (int w = 0; w < 8; ++w) M = fmaxf(M, red[w][150]);
            float s = 0.f, ss = 0.f, L = 0.f, A = 0.f;
            float mxv = -INFINITY, mnv = INFINITY;
            #pragma unroll
            for (int w = 0; w < 8; ++w) {
                s  += red[w][tid];
                ss += red[w][30 + tid];
                mxv = fmaxf(mxv, red[w][60 + tid]);
                mnv = fminf(mnv, red[w][90 + tid]);
                float e = __expf(red[w][150] - M);
                L = fmaf(red[w][151], e, L);
                A = fmaf(red[w][120 + tid], e, A);
            }
            const float invN = 1.f / (float)NN;
            float mean = s * invN;
            float var  = fmaxf(ss * invN - mean * mean, 0.f);
            feat[tid]       = mean;
            feat[30 + tid]  = mxv;
            feat[60 + tid]  = mnv;
            feat[90 + tid]  = sqrtf(var);
            feat[120 + tid] = s;
            feat[150 + tid] = A / L;
        }
    }
    __syncthreads();

    // ---------------- head MLP: 180 -> 40 -> 40 -> 5 ----------------
    if (tid < 480) {      // layer 1 distributed: 12 partials x 40 outputs (weights pre-hoisted)
        int o = tid % 40, p = tid / 40;
        float z = 0.f;
        #pragma unroll
        for (int ii = 0; ii < 15; ++ii)
            z = fmaf(feat[p * 15 + ii], wf1r[ii], z);
        redh[p][o] = z;
    }
    __syncthreads();
    if (tid < 40) {
        float z = bf1r;
        #pragma unroll
        for (int p = 0; p < 12; ++p) z += redh[p][tid];
        z1s[tid] = fmaxf(z, 0.f);
    }
    __syncthreads();
    if (tid < 40) {
        float z = bf2r;
        #pragma unroll
        for (int i = 0; i < 40; ++i) z = fmaf(z1s[i], wf2s[i * 40 + tid], z);
        z2s[tid] = fmaxf(z, 0.f);
    }
    __syncthreads();
    if (tid < 5) {
        float o = bf3r;
        #pragma unroll
        for (int i = 0; i < 40; ++i) o = fmaf(z2s[i], wf3s[i * 5 + tid], o);
        out[b * 5 + tid] = o;
    }
}

extern "C" void kernel_launch(void* const* d_in, const int* in_sizes, int n_in,
                              void* d_out, int out_size, void* d_ws, size_t ws_size,
                              hipStream_t stream) {
    const float* x   = (const float*)d_in[0];
    const float* W1  = (const float*)d_in[1];
    const float* b1  = (const float*)d_in[2];
    const float* W2  = (const float*)d_in[3];
    const float* b2  = (const float*)d_in[4];
    const float* Wa1 = (const float*)d_in[5];
    const float* ba1 = (const float*)d_in[6];
    const float* Wa2 = (const float*)d_in[7];
    const float* ba2 = (const float*)d_in[8];
    const float* Wf1 = (const float*)d_in[9];
    const float* bf1 = (const float*)d_in[10];
    const float* Wf2 = (const float*)d_in[11];
    const float* bf2 = (const float*)d_in[12];
    const float* Wf3 = (const float*)d_in[13];
    const float* bf3 = (const float*)d_in[14];
    float* out = (float*)d_out;

    pointnet_pwl5_kernel<<<256, TPB, 0, stream>>>(
        x, W1, b1, W2, b2, Wa1, ba1, Wa2, ba2,
        Wf1, bf1, Wf2, bf2, Wf3, bf3, out);
}

// Round 8
// 113.606 us; speedup vs baseline: 1.0443x; 1.0443x over previous
//
#include <hip/hip_runtime.h>
#include <math.h>

#define NN 8192
#define HH 30
#define TPB 1024
#define NIV 31      // coarse intervals (fallback)
#define TSTR 68     // fallback table row stride (floats)

__launch_bounds__(TPB)
__global__ void pointnet_pwl7_kernel(
    const float* __restrict__ x,
    const float* __restrict__ W1,  const float* __restrict__ b1,
    const float* __restrict__ W2,  const float* __restrict__ b2,
    const float* __restrict__ Wa1, const float* __restrict__ ba1,
    const float* __restrict__ Wa2, const float* __restrict__ ba2,
    const float* __restrict__ Wf1, const float* __restrict__ bf1,
    const float* __restrict__ Wf2, const float* __restrict__ bf2,
    const float* __restrict__ Wf3, const float* __restrict__ bf3,
    float* __restrict__ out)
{
    // raw weights
    __shared__ float W2s[HH][32];
    __shared__ float Wa1s[HH][32];
    __shared__ float P[HH][32];                 // W2*Wa1
    __shared__ float w1s[HH], b1s[HH], tts[HH];
    __shared__ float b2s[32], ba1s[32], Wa2s[32], vb2[32];
    __shared__ int   DcS;
    __shared__ float d0S;
    // fast path (Dc==1)
    __shared__ __align__(16) float ab2[2][64];  // [a0..a31 | b0..b31]
    __shared__ __align__(16) float uv2[2][64];  // [u0..u31 | v0..v31]
    __shared__ float zz_raw[128], zz_s[128];
    __shared__ float2 gcs[129];
    // fallback
    __shared__ __align__(16) float ts_s[32];
    __shared__ int   rnk[HH];
    __shared__ __align__(16) float abt[NIV][TSTR];
    __shared__ __align__(16) float uvt[NIV][TSTR];
    // reductions / epilogue
    __shared__ float redb[16][155];
    __shared__ float fin[16];
    __shared__ float feat[192];
    __shared__ float redh[12][40];
    __shared__ float z1s[40], z2s[40];
    __shared__ float wf1s[180 * 40];
    __shared__ float wf2s[40 * 40];
    __shared__ float wf3s[40 * 5];
    __shared__ float bf1s[40], bf2s[40], bf3s[8];

    const int tid = threadIdx.x;
    const int b   = blockIdx.x;

    // ---- x prefetch FIRST (8 VGPR), hides HBM latency under the preamble ----
    float4 xl0, xl1;
    {
        const float4* xb4 = reinterpret_cast<const float4*>(x + (size_t)b * NN);
        xl0 = xb4[tid];
        xl1 = xb4[tid + TPB];
    }

    // ---------------- Phase A: stage everything to LDS ----------------
    for (int i = tid; i < HH * 32; i += TPB) {
        int j = i >> 5, k = i & 31;
        W2s[j][k] = (k < HH) ? W2[j * HH + k] : 0.f;
    }
    for (int i = tid; i < HH * 32; i += TPB) ((float*)Wa1s)[i] = Wa1[i];
    for (int i = tid; i < 180 * 40; i += TPB) wf1s[i] = Wf1[i];
    for (int i = tid; i < 40 * 40;  i += TPB) wf2s[i] = Wf2[i];
    if (tid < 40 * 5) wf3s[tid] = Wf3[tid];
    if (tid < HH) {
        float w = W1[tid], bb = b1[tid];
        w1s[tid] = w; b1s[tid] = bb;
        tts[tid] = (w != 0.f) ? (-bb / w) : INFINITY;
    }
    if (tid < 32) {
        b2s[tid]  = (tid < HH) ? b2[tid] : 0.f;
        ba1s[tid] = ba1[tid];
        Wa2s[tid] = Wa2[tid];
        ts_s[tid] = INFINITY;
    }
    if (tid < 40) { bf1s[tid] = bf1[tid]; bf2s[tid] = bf2[tid]; }
    if (tid < 5)  { bf3s[tid] = bf3[tid]; }
    const float ba2v = ba2[0];
    __syncthreads();

    // ---------------- Phase B: P, vb2 (992 thr, 1 elem each) || Dc detect (wave 0) ----------------
    if (tid < HH * 32) {
        int j = tid >> 5, m = tid & 31;
        float s = 0.f;
        #pragma unroll
        for (int k = 0; k < HH; ++k) s = fmaf(W2s[j][k], Wa1s[k][m], s);
        P[j][m] = s;
    } else if (tid < HH * 32 + 32) {
        int m = tid - HH * 32;
        float s = 0.f;
        #pragma unroll
        for (int k = 0; k < HH; ++k) s = fmaf(Wa1s[k][m], b2s[k], s);
        vb2[m] = s;
    }
    if (tid < 64) {
        float t = (tid < HH) ? tts[tid] : INFINITY;
        bool fin_t = (t < INFINITY);
        float tmin = fin_t ? t :  INFINITY;
        float tmax = fin_t ? t : -INFINITY;
        #pragma unroll
        for (int off = 32; off > 0; off >>= 1) {
            tmin = fminf(tmin, __shfl_xor(tmin, off));
            tmax = fmaxf(tmax, __shfl_xor(tmax, off));
        }
        if (tid == 0) {
            bool dc1 = (tmin < INFINITY) && (tmin == tmax);
            DcS = dc1 ? 1 : 0;
            d0S = tmin;
        }
    }
    __syncthreads();

    if (DcS == 1) {
        // ================= FAST PATH: one shared breakpoint d0 =================
        const float d0 = d0S;
        // activity by sign: row0 (x<d0): w<0 ; row1 (x>d0): w>0 ; w==0: b1>0 (both rows)

        // ---- Phase C (fused): ab2 || uv2+zz zeros || zz pads ----
        if (tid < 64) {
            int r = tid >> 5, k = tid & 31;
            float a = 0.f, bb = 0.f;
            if (k < HH) {
                for (int j = 0; j < HH; ++j) {
                    float w = w1s[j];
                    bool act = (w == 0.f) ? (b1s[j] > 0.f) : (r ? (w > 0.f) : (w < 0.f));
                    if (act) {
                        float w2 = W2s[j][k];
                        a  = fmaf(w,      w2, a);
                        bb = fmaf(b1s[j], w2, bb);
                    }
                }
                bb += b2s[k];
            }
            ab2[r][k]      = a;
            ab2[r][32 + k] = bb;
        } else if (tid < 128) {
            int i2 = tid - 64;
            int r = i2 >> 5, m = i2 & 31;
            float u = 0.f, v = 0.f;
            for (int j = 0; j < HH; ++j) {
                float w = w1s[j];
                bool act = (w == 0.f) ? (b1s[j] > 0.f) : (r ? (w > 0.f) : (w < 0.f));
                if (act) {
                    float pj = P[j][m];
                    u = fmaf(w,      pj, u);
                    v = fmaf(b1s[j], pj, v);
                }
            }
            v += vb2[m] + ba1s[m];
            uv2[r][m]      = u;
            uv2[r][32 + m] = v;
            float zr = -v / u;
            bool ok = (u != 0.f) && (r == 0 ? (zr < d0) : (zr > d0));
            zz_raw[1 + i2] = ok ? zr : INFINITY;
        } else if (tid < 191) {
            zz_raw[tid - 63] = INFINITY;   // pads 65..127
        } else if (tid == 191) {
            zz_raw[0] = d0;
        }
        __syncthreads();

        // ---- Phase D: stable rank sort of 128 refined breakpoints ----
        if (tid < 128) {
            float v = zz_raw[tid];
            int rk = 0;
            for (int i = 0; i < 128; ++i) {
                float vi = zz_raw[i];
                rk += (vi < v) || (vi == v && i < tid);
            }
            zz_s[rk] = v;
        }
        __syncthreads();

        // ---- Phase E: (g,c) per refined interval via interior test point ----
        if (tid < 129) {
            float lo = (tid == 0)   ? -INFINITY : zz_s[tid - 1];
            float hi = (tid == 128) ?  INFINITY : zz_s[tid];
            float xm;
            if (lo == -INFINITY)      xm = (hi < INFINITY) ? hi - 1.f : 0.f;
            else if (hi == INFINITY)  xm = lo + 1.f;
            else                      xm = 0.5f * (lo + hi);
            int r = (xm >= d0) ? 1 : 0;
            float g = 0.f, c = ba2v;
            for (int m = 0; m < 32; ++m) {
                float u = uv2[r][m], v = uv2[r][32 + m];
                if (fmaf(u, xm, v) > 0.f) {
                    float w = Wa2s[m];
                    g = fmaf(w, u, g);
                    c = fmaf(w, v, c);
                }
            }
            gcs[tid] = make_float2(g, c);
        }
        __syncthreads();

        // ---- main loop: 8 points/thread, pure VALU + small LDS ----
        float c0=0,c1=0, Sx0=0,Sx1=0, Q0=0,Q1=0;
        float mn0=INFINITY,mn1=INFINITY, mx0=-INFINITY,mx1=-INFINITY;
        float Sp0=0,Sp1=0, Px0=0,Px1=0;
        float mrun = -INFINITY;

        float xs[8] = {xl0.x, xl0.y, xl0.z, xl0.w, xl1.x, xl1.y, xl1.z, xl1.w};
        #pragma unroll
        for (int pp = 0; pp < 8; ++pp) {
            float xv = xs[pp];
            bool q1 = (xv >= d0);
            int idx = 0;
            #pragma unroll
            for (int bit = 64; bit >= 1; bit >>= 1) {
                int t = idx + bit;
                idx = (zz_s[t - 1] <= xv) ? t : idx;
            }
            float2 gc = gcs[idx];
            float l = fmaf(xv, gc.x, gc.y);
            float dlt = l - mrun, p;
            if (dlt > 8.f) {                 // rare; also first point (mrun=-INF)
                float sc = __expf(-dlt);
                Sp0 *= sc; Sp1 *= sc; Px0 *= sc; Px1 *= sc;
                mrun = l; p = 1.f;
            } else p = __expf(dlt);
            float xx = xv * xv, px = p * xv;
            float i1 = q1 ? 1.f : 0.f, i0 = 1.f - i1;
            c0 += i0;                    c1 += i1;
            Sx0 = fmaf(i0, xv, Sx0);     Sx1 = fmaf(i1, xv, Sx1);
            Q0  = fmaf(i0, xx, Q0);      Q1  = fmaf(i1, xx, Q1);
            Sp0 = fmaf(i0, p,  Sp0);     Sp1 = fmaf(i1, p,  Sp1);
            Px0 = fmaf(i0, px, Px0);     Px1 = fmaf(i1, px, Px1);
            mn0 = fminf(mn0, q1 ?  INFINITY : xv);
            mx0 = fmaxf(mx0, q1 ? -INFINITY : xv);
            mn1 = fminf(mn1, q1 ? xv :  INFINITY);
            mx1 = fmaxf(mx1, q1 ? xv : -INFINITY);
        }

        // ---- wave butterfly (15 quantities) ----
        #pragma unroll 1
        for (int off = 32; off > 0; off >>= 1) {
            c0  += __shfl_xor(c0,  off);  c1  += __shfl_xor(c1,  off);
            Sx0 += __shfl_xor(Sx0, off);  Sx1 += __shfl_xor(Sx1, off);
            Q0  += __shfl_xor(Q0,  off);  Q1  += __shfl_xor(Q1,  off);
            mn0 = fminf(mn0, __shfl_xor(mn0, off));
            mn1 = fminf(mn1, __shfl_xor(mn1, off));
            mx0 = fmaxf(mx0, __shfl_xor(mx0, off));
            mx1 = fmaxf(mx1, __shfl_xor(mx1, off));
            float mo = __shfl_xor(mrun, off);
            float M  = fmaxf(mrun, mo);
            float sa = __expf(mrun - M), sb = __expf(mo - M);
            float t;
            t = __shfl_xor(Sp0, off); Sp0 = Sp0 * sa + t * sb;
            t = __shfl_xor(Sp1, off); Sp1 = Sp1 * sa + t * sb;
            t = __shfl_xor(Px0, off); Px0 = Px0 * sa + t * sb;
            t = __shfl_xor(Px1, off); Px1 = Px1 * sa + t * sb;
            mrun = M;
        }

        const int wave = tid >> 6, lane = tid & 63;
        if (lane == 0) {
            float* rw = redb[wave];
            rw[0]=c0; rw[1]=Sx0; rw[2]=Q0; rw[3]=mn0; rw[4]=mx0; rw[5]=Sp0; rw[6]=Px0;
            rw[7]=c1; rw[8]=Sx1; rw[9]=Q1; rw[10]=mn1; rw[11]=mx1; rw[12]=Sp1; rw[13]=Px1;
            rw[14]=mrun;
        }
        __syncthreads();

        if (tid < 2) {
            float M = redb[0][14];
            #pragma unroll
            for (int w = 1; w < 16; ++w) M = fmaxf(M, redb[w][14]);
            int base = tid * 7;
            float ck=0, Sx=0, Q=0, mnv=INFINITY, mxv=-INFINITY, Sp=0, Px=0;
            #pragma unroll
            for (int w = 0; w < 16; ++w) {
                ck += redb[w][base+0]; Sx += redb[w][base+1]; Q += redb[w][base+2];
                mnv = fminf(mnv, redb[w][base+3]); mxv = fmaxf(mxv, redb[w][base+4]);
                float e = __expf(redb[w][14] - M);
                Sp = fmaf(redb[w][base+5], e, Sp);
                Px = fmaf(redb[w][base+6], e, Px);
            }
            fin[base+0]=ck; fin[base+1]=Sx; fin[base+2]=Q;
            fin[base+3]=mnv; fin[base+4]=mxv; fin[base+5]=Sp; fin[base+6]=Px;
        }
        __syncthreads();

        if (tid < HH) {
            float sumk=0, ssqk=0, acck=0, L=0;
            float mxk=-INFINITY, mnk=INFINITY;
            #pragma unroll
            for (int r2 = 0; r2 < 2; ++r2) {
                float ck = fin[r2*7+0], Sx = fin[r2*7+1], Q = fin[r2*7+2];
                float xmn = fin[r2*7+3], xmx = fin[r2*7+4];
                float Sp = fin[r2*7+5], Px = fin[r2*7+6];
                float a = ab2[r2][tid], bb = ab2[r2][32 + tid];
                sumk += a * Sx + bb * ck;
                ssqk += a * a * Q + 2.f * a * bb * Sx + bb * bb * ck;
                acck += a * Px + bb * Sp;
                L += Sp;
                if (ck > 0.f) {
                    float h1 = fmaf(a, xmn, bb), h2v = fmaf(a, xmx, bb);
                    mxk = fmaxf(mxk, fmaxf(h1, h2v));
                    mnk = fminf(mnk, fminf(h1, h2v));
                }
            }
            const float invN = 1.f / (float)NN;
            float mean = sumk * invN;
            float var  = fmaxf(ssqk * invN - mean * mean, 0.f);
            feat[tid]        = mean;
            feat[30 + tid]   = mxk;
            feat[60 + tid]   = mnk;
            feat[90 + tid]   = sqrtf(var);
            feat[120 + tid]  = sumk;
            feat[150 + tid]  = acck / L;
        }
    } else {
        // ================= FALLBACK: general coarse-table per-point path =================
        if (tid < HH) {      // rank sort
            float t = tts[tid];
            int r = 0;
            for (int i = 0; i < HH; ++i) {
                float ti = tts[i];
                r += (ti < t) || (ti == t && i < tid);
            }
            ts_s[r] = t;
            rnk[tid] = r;
        }
        __syncthreads();
        for (int idx = tid; idx < NIV * 32; idx += TPB) {
            int r = idx >> 5, k = idx & 31;
            float a = 0.f, bb = 0.f;
            if (k < HH) {
                for (int j = 0; j < HH; ++j) {
                    float w = w1s[j];
                    bool act = (w > 0.f) ? (rnk[j] < r)
                             : ((w < 0.f) ? (rnk[j] >= r) : (b1s[j] > 0.f));
                    if (act) {
                        float w2 = W2s[j][k];
                        a  = fmaf(w,      w2, a);
                        bb = fmaf(b1s[j], w2, bb);
                    }
                }
                bb += b2s[k];
            }
            abt[r][k]      = a;
            abt[r][32 + k] = bb;
        }
        __syncthreads();
        for (int idx = tid; idx < NIV * 32; idx += TPB) {
            int r = idx >> 5, m = idx & 31;
            float u = 0.f, v = 0.f;
            for (int k = 0; k < HH; ++k) {
                float wa = Wa1s[k][m];
                u = fmaf(wa, abt[r][k],      u);
                v = fmaf(wa, abt[r][32 + k], v);
            }
            v += ba1s[m];
            uvt[r][m]      = u;
            uvt[r][32 + m] = v;
        }
        __syncthreads();

        float sum[HH], ssq[HH], mx[HH], mn[HH], acc[HH];
        #pragma unroll
        for (int k = 0; k < HH; ++k) {
            sum[k] = 0.f; ssq[k] = 0.f; acc[k] = 0.f;
            mx[k] = -INFINITY; mn[k] = INFINITY;
        }
        float mrun = -INFINITY, lrun = 0.f;
        const float* xb = x + (size_t)b * NN;
        const float4* ts4 = (const float4*)ts_s;
        const float4* wv4 = (const float4*)Wa2s;

        #pragma unroll 1
        for (int it = 0; it < NN / TPB; ++it) {
            float xv = xb[it * TPB + tid];
            int r = 0;
            #pragma unroll
            for (int i = 0; i < 8; ++i) {
                float4 t = ts4[i];
                r += (xv >= t.x) ? 1 : 0;
                r += (xv >= t.y) ? 1 : 0;
                r += (xv >= t.z) ? 1 : 0;
                r += (xv >= t.w) ? 1 : 0;
            }
            float h2[HH];
            const float4* arow = (const float4*)(&abt[r][0]);
            #pragma unroll
            for (int i = 0; i < 7; ++i) {
                float4 av = arow[i], bv = arow[8 + i];
                h2[4*i+0] = fmaf(xv, av.x, bv.x);
                h2[4*i+1] = fmaf(xv, av.y, bv.y);
                h2[4*i+2] = fmaf(xv, av.z, bv.z);
                h2[4*i+3] = fmaf(xv, av.w, bv.w);
            }
            { float4 av = arow[7], bv = arow[15];
              h2[28] = fmaf(xv, av.x, bv.x);
              h2[29] = fmaf(xv, av.y, bv.y); }
            #pragma unroll
            for (int k = 0; k < HH; ++k) {
                float h = h2[k];
                sum[k] += h;
                ssq[k] = fmaf(h, h, ssq[k]);
                mx[k] = fmaxf(mx[k], h);
                mn[k] = fminf(mn[k], h);
            }
            float l = ba2v;
            const float4* urow = (const float4*)(&uvt[r][0]);
            #pragma unroll
            for (int i = 0; i < 8; ++i) {
                float4 uu = urow[i], vv = urow[8 + i], ww = wv4[i];
                l = fmaf(fmaxf(fmaf(xv, uu.x, vv.x), 0.f), ww.x, l);
                l = fmaf(fmaxf(fmaf(xv, uu.y, vv.y), 0.f), ww.y, l);
                l = fmaf(fmaxf(fmaf(xv, uu.z, vv.z), 0.f), ww.z, l);
                l = fmaf(fmaxf(fmaf(xv, uu.w, vv.w), 0.f), ww.w, l);
            }
            float d = l - mrun, p;
            if (d > 8.f) {
                float s = __expf(-d);
                lrun *= s;
                #pragma unroll
                for (int k = 0; k < HH; ++k) acc[k] *= s;
                mrun = l; p = 1.f;
            } else p = __expf(d);
            lrun += p;
            #pragma unroll
            for (int k = 0; k < HH; ++k) acc[k] = fmaf(p, h2[k], acc[k]);
        }

        #pragma unroll 1
        for (int off = 32; off > 0; off >>= 1) {
            #pragma unroll
            for (int k = 0; k < HH; ++k) {
                sum[k] += __shfl_xor(sum[k], off);
                ssq[k] += __shfl_xor(ssq[k], off);
                mx[k] = fmaxf(mx[k], __shfl_xor(mx[k], off));
                mn[k] = fminf(mn[k], __shfl_xor(mn[k], off));
            }
            float mo = __shfl_xor(mrun, off);
            float lo = __shfl_xor(lrun, off);
            float M  = fmaxf(mrun, mo);
            float sa = __expf(mrun - M), sb = __expf(mo - M);
            lrun = lrun * sa + lo * sb;
            #pragma unroll
            for (int k = 0; k < HH; ++k)
                acc[k] = acc[k] * sa + __shfl_xor(acc[k], off) * sb;
            mrun = M;
        }

        const int wave = tid >> 6, lane = tid & 63;
        if (lane == 0) {
            #pragma unroll
            for (int k = 0; k < HH; ++k) {
                redb[wave][k]       = sum[k];
                redb[wave][30 + k]  = ssq[k];
                redb[wave][60 + k]  = mx[k];
                redb[wave][90 + k]  = mn[k];
                redb[wave][120 + k] = acc[k];
            }
            redb[wave][150] = mrun;
            redb[wave][151] = lrun;
        }
        __syncthreads();

        if (tid < HH) {
            float M = -INFINITY;
            #pragma unroll
            for (int w = 0; w < 16; ++w) M = fmaxf(M, redb[w][150]);
            float s = 0.f, ss = 0.f, L = 0.f, A = 0.f;
            float mxv = -INFINITY, mnv = INFINITY;
            #pragma unroll
            for (int w = 0; w < 16; ++w) {
                s  += redb[w][tid];
                ss += redb[w][30 + tid];
                mxv = fmaxf(mxv, redb[w][60 + tid]);
                mnv = fminf(mnv, redb[w][90 + tid]);
                float e = __expf(redb[w][150] - M);
                L = fmaf(redb[w][151], e, L);
                A = fmaf(redb[w][120 + tid], e, A);
            }
            const float invN = 1.f / (float)NN;
            float mean = s * invN;
            float var  = fmaxf(ss * invN - mean * mean, 0.f);
            feat[tid]       = mean;
            feat[30 + tid]  = mxv;
            feat[60 + tid]  = mnv;
            feat[90 + tid]  = sqrtf(var);
            feat[120 + tid] = s;
            feat[150 + tid] = A / L;
        }
    }
    __syncthreads();

    // ---------------- head MLP: 180 -> 40 -> 40 -> 5 (weights in LDS) ----------------
    if (tid < 480) {      // layer 1 distributed: 12 partials x 40 outputs
        int o = tid % 40, p = tid / 40;
        float z = 0.f;
        #pragma unroll
        for (int ii = 0; ii < 15; ++ii)
            z = fmaf(feat[p * 15 + ii], wf1s[(p * 15 + ii) * 40 + o], z);
        redh[p][o] = z;
    }
    __syncthreads();
    if (tid < 40) {
        float z = bf1s[tid];
        #pragma unroll
        for (int p = 0; p < 12; ++p) z += redh[p][tid];
        z1s[tid] = fmaxf(z, 0.f);
    }
    __syncthreads();
    if (tid < 40) {
        float z = bf2s[tid];
        #pragma unroll
        for (int i = 0; i < 40; ++i) z = fmaf(z1s[i], wf2s[i * 40 + tid], z);
        z2s[tid] = fmaxf(z, 0.f);
    }
    __syncthreads();
    if (tid < 5) {
        float o = bf3s[tid];
        #pragma unroll
        for (int i = 0; i < 40; ++i) o = fmaf(z2s[i], wf3s[i * 5 + tid], o);
        out[b * 5 + tid] = o;
    }
}

extern "C" void kernel_launch(void* const* d_in, const int* in_sizes, int n_in,
                              void* d_out, int out_size, void* d_ws, size_t ws_size,
                              hipStream_t stream) {
    const float* x   = (const float*)d_in[0];
    const float* W1  = (const float*)d_in[1];
    const float* b1  = (const float*)d_in[2];
    const float* W2  = (const float*)d_in[3];
    const float* b2  = (const float*)d_in[4];
    const float* Wa1 = (const float*)d_in[5];
    const float* ba1 = (const float*)d_in[6];
    const float* Wa2 = (const float*)d_in[7];
    const float* ba2 = (const float*)d_in[8];
    const float* Wf1 = (const float*)d_in[9];
    const float* bf1 = (const float*)d_in[10];
    const float* Wf2 = (const float*)d_in[11];
    const float* bf2 = (const float*)d_in[12];
    const float* Wf3 = (const float*)d_in[13];
    const float* bf3 = (const float*)d_in[14];
    float* out = (float*)d_out;

    pointnet_pwl7_kernel<<<256, TPB, 0, stream>>>(
        x, W1, b1, W2, b2, Wa1, ba1, Wa2, ba2,
        Wf1, bf1, Wf2, bf2, Wf3, bf3, out);
}

// Round 10
// 107.427 us; speedup vs baseline: 1.1044x; 1.0575x over previous
//
#include <hip/hip_runtime.h>
#include <math.h>

#define NN 8192
#define HH 30
#define TPBA 1024
#define TPBB 512
#define NIV 31      // coarse intervals (fallback kernel)
#define TSTR 68     // fallback table row stride (floats)

// ===================== Kernel A: Dc==1 fast path only =====================
__launch_bounds__(TPBA)
__global__ void pointnet_fastA(
    const float* __restrict__ x,
    const float* __restrict__ W1,  const float* __restrict__ b1,
    const float* __restrict__ W2,  const float* __restrict__ b2,
    const float* __restrict__ Wa1, const float* __restrict__ ba1,
    const float* __restrict__ Wa2, const float* __restrict__ ba2,
    const float* __restrict__ Wf1, const float* __restrict__ bf1,
    const float* __restrict__ Wf2, const float* __restrict__ bf2,
    const float* __restrict__ Wf3, const float* __restrict__ bf3,
    float* __restrict__ out, int* __restrict__ wsflag)
{
    __shared__ float W2s[HH][32];
    __shared__ float Wa1s[HH][32];
    __shared__ float P[HH][32];                 // W2*Wa1
    __shared__ float w1s[HH], b1s[HH], tts[HH];
    __shared__ float b2s[32], ba1s[32], Wa2s[32], vb2[32];
    __shared__ int   DcS;
    __shared__ float d0S;
    __shared__ __align__(16) float ab2[2][64];  // [a0..a31 | b0..b31]
    __shared__ __align__(16) float uv2[2][64];  // [u0..u31 | v0..v31]
    __shared__ float zz_raw[128], zz_s[128];
    __shared__ float2 gcs[129];
    __shared__ float redb[16][16];
    __shared__ float fin[16];
    __shared__ float feat[192];
    __shared__ float redh[12][40];
    __shared__ float z1s[40], z2s[40];
    __shared__ float wf1s[180 * 40];
    __shared__ float wf2s[40 * 40];
    __shared__ float wf3s[40 * 5];
    __shared__ float bf1s[40], bf2s[40], bf3s[8];

    const int tid = threadIdx.x;
    const int b   = blockIdx.x;

    // ---- x prefetch first: HBM latency hides under the preamble ----
    float4 xl0, xl1;
    {
        const float4* xb4 = reinterpret_cast<const float4*>(x + (size_t)b * NN);
        xl0 = xb4[tid];
        xl1 = xb4[tid + TPBA];
    }

    // ---- Phase A: stage to LDS ----
    for (int i = tid; i < HH * 32; i += TPBA) {
        int j = i >> 5, k = i & 31;
        W2s[j][k] = (k < HH) ? W2[j * HH + k] : 0.f;
    }
    for (int i = tid; i < HH * 32; i += TPBA) ((float*)Wa1s)[i] = Wa1[i];
    for (int i = tid; i < 180 * 40; i += TPBA) wf1s[i] = Wf1[i];
    for (int i = tid; i < 40 * 40;  i += TPBA) wf2s[i] = Wf2[i];
    if (tid < 40 * 5) wf3s[tid] = Wf3[tid];
    if (tid < HH) {
        float w = W1[tid], bb = b1[tid];
        w1s[tid] = w; b1s[tid] = bb;
        tts[tid] = (w != 0.f) ? (-bb / w) : INFINITY;
    }
    if (tid < 32) {
        b2s[tid]  = (tid < HH) ? b2[tid] : 0.f;
        ba1s[tid] = ba1[tid];
        Wa2s[tid] = Wa2[tid];
    }
    if (tid < 40) { bf1s[tid] = bf1[tid]; bf2s[tid] = bf2[tid]; }
    if (tid < 5)  { bf3s[tid] = bf3[tid]; }
    const float ba2v = ba2[0];
    __syncthreads();

    // ---- Phase B: P, vb2 || Dc detect (wave 0) ----
    if (tid < HH * 32) {
        int j = tid >> 5, m = tid & 31;
        float s = 0.f;
        #pragma unroll
        for (int k = 0; k < HH; ++k) s = fmaf(W2s[j][k], Wa1s[k][m], s);
        P[j][m] = s;
    } else if (tid < HH * 32 + 32) {
        int m = tid - HH * 32;
        float s = 0.f;
        #pragma unroll
        for (int k = 0; k < HH; ++k) s = fmaf(Wa1s[k][m], b2s[k], s);
        vb2[m] = s;
    }
    if (tid < 64) {
        float t = (tid < HH) ? tts[tid] : INFINITY;
        bool fin_t = (t < INFINITY);
        float tmin = fin_t ? t :  INFINITY;
        float tmax = fin_t ? t : -INFINITY;
        #pragma unroll
        for (int off = 32; off > 0; off >>= 1) {
            tmin = fminf(tmin, __shfl_xor(tmin, off));
            tmax = fmaxf(tmax, __shfl_xor(tmax, off));
        }
        if (tid == 0) {
            bool dc1 = (tmin < INFINITY) && (tmin == tmax);
            DcS = dc1 ? 1 : 0;
            d0S = tmin;
        }
    }
    __syncthreads();

    if (tid == 0) wsflag[0] = DcS;   // every block writes same value: benign
    if (DcS != 1) return;            // block-uniform: kernel B will handle it

    const float d0 = d0S;
    // activity by sign: row0 (x<d0): w<0 ; row1 (x>d0): w>0 ; w==0: b1>0

    // ---- Phase C (fused): ab2 || uv2 + zz zeros || pads ----
    if (tid < 64) {
        int r = tid >> 5, k = tid & 31;
        float a = 0.f, bb = 0.f;
        if (k < HH) {
            for (int j = 0; j < HH; ++j) {
                float w = w1s[j];
                bool act = (w == 0.f) ? (b1s[j] > 0.f) : (r ? (w > 0.f) : (w < 0.f));
                if (act) {
                    float w2 = W2s[j][k];
                    a  = fmaf(w,      w2, a);
                    bb = fmaf(b1s[j], w2, bb);
                }
            }
            bb += b2s[k];
        }
        ab2[r][k]      = a;
        ab2[r][32 + k] = bb;
    } else if (tid < 128) {
        int i2 = tid - 64;
        int r = i2 >> 5, m = i2 & 31;
        float u = 0.f, v = 0.f;
        for (int j = 0; j < HH; ++j) {
            float w = w1s[j];
            bool act = (w == 0.f) ? (b1s[j] > 0.f) : (r ? (w > 0.f) : (w < 0.f));
            if (act) {
                float pj = P[j][m];
                u = fmaf(w,      pj, u);
                v = fmaf(b1s[j], pj, v);
            }
        }
        v += vb2[m] + ba1s[m];
        uv2[r][m]      = u;
        uv2[r][32 + m] = v;
        float zr = -v / u;
        bool ok = (u != 0.f) && (r == 0 ? (zr < d0) : (zr > d0));
        zz_raw[1 + i2] = ok ? zr : INFINITY;
    } else if (tid < 191) {
        zz_raw[tid - 63] = INFINITY;   // pads 65..127
    } else if (tid == 191) {
        zz_raw[0] = d0;
    }
    __syncthreads();

    // ---- Phase D: stable rank sort of 128 refined breakpoints ----
    if (tid < 128) {
        float v = zz_raw[tid];
        int rk = 0;
        for (int i = 0; i < 128; ++i) {
            float vi = zz_raw[i];
            rk += (vi < v) || (vi == v && i < tid);
        }
        zz_s[rk] = v;
    }
    __syncthreads();

    // ---- Phase E: (g,c) per refined interval ----
    if (tid < 129) {
        float lo = (tid == 0)   ? -INFINITY : zz_s[tid - 1];
        float hi = (tid == 128) ?  INFINITY : zz_s[tid];
        float xm;
        if (lo == -INFINITY)      xm = (hi < INFINITY) ? hi - 1.f : 0.f;
        else if (hi == INFINITY)  xm = lo + 1.f;
        else                      xm = 0.5f * (lo + hi);
        int r = (xm >= d0) ? 1 : 0;
        float g = 0.f, c = ba2v;
        for (int m = 0; m < 32; ++m) {
            float u = uv2[r][m], v = uv2[r][32 + m];
            if (fmaf(u, xm, v) > 0.f) {
                float w = Wa2s[m];
                g = fmaf(w, u, g);
                c = fmaf(w, v, c);
            }
        }
        gcs[tid] = make_float2(g, c);
    }
    __syncthreads();

    // ---- main loop: 8 points/thread ----
    float c0=0,c1=0, Sx0=0,Sx1=0, Q0=0,Q1=0;
    float mn0=INFINITY,mn1=INFINITY, mx0=-INFINITY,mx1=-INFINITY;
    float Sp0=0,Sp1=0, Px0=0,Px1=0;
    float mrun = -INFINITY;

    float xs[8] = {xl0.x, xl0.y, xl0.z, xl0.w, xl1.x, xl1.y, xl1.z, xl1.w};
    #pragma unroll
    for (int pp = 0; pp < 8; ++pp) {
        float xv = xs[pp];
        bool q1 = (xv >= d0);
        int idx = 0;
        #pragma unroll
        for (int bit = 64; bit >= 1; bit >>= 1) {
            int t = idx + bit;
            idx = (zz_s[t - 1] <= xv) ? t : idx;
        }
        float2 gc = gcs[idx];
        float l = fmaf(xv, gc.x, gc.y);
        float dlt = l - mrun, p;
        if (dlt > 8.f) {
            float sc = __expf(-dlt);
            Sp0 *= sc; Sp1 *= sc; Px0 *= sc; Px1 *= sc;
            mrun = l; p = 1.f;
        } else p = __expf(dlt);
        float xx = xv * xv, px = p * xv;
        float i1 = q1 ? 1.f : 0.f, i0 = 1.f - i1;
        c0 += i0;                    c1 += i1;
        Sx0 = fmaf(i0, xv, Sx0);     Sx1 = fmaf(i1, xv, Sx1);
        Q0  = fmaf(i0, xx, Q0);      Q1  = fmaf(i1, xx, Q1);
        Sp0 = fmaf(i0, p,  Sp0);     Sp1 = fmaf(i1, p,  Sp1);
        Px0 = fmaf(i0, px, Px0);     Px1 = fmaf(i1, px, Px1);
        mn0 = fminf(mn0, q1 ?  INFINITY : xv);
        mx0 = fmaxf(mx0, q1 ? -INFINITY : xv);
        mn1 = fminf(mn1, q1 ? xv :  INFINITY);
        mx1 = fmaxf(mx1, q1 ? xv : -INFINITY);
    }

    // ---- wave butterfly (15 quantities) ----
    #pragma unroll 1
    for (int off = 32; off > 0; off >>= 1) {
        c0  += __shfl_xor(c0,  off);  c1  += __shfl_xor(c1,  off);
        Sx0 += __shfl_xor(Sx0, off);  Sx1 += __shfl_xor(Sx1, off);
        Q0  += __shfl_xor(Q0,  off);  Q1  += __shfl_xor(Q1,  off);
        mn0 = fminf(mn0, __shfl_xor(mn0, off));
        mn1 = fminf(mn1, __shfl_xor(mn1, off));
        mx0 = fmaxf(mx0, __shfl_xor(mx0, off));
        mx1 = fmaxf(mx1, __shfl_xor(mx1, off));
        float mo = __shfl_xor(mrun, off);
        float M  = fmaxf(mrun, mo);
        float sa = __expf(mrun - M), sb = __expf(mo - M);
        float t;
        t = __shfl_xor(Sp0, off); Sp0 = Sp0 * sa + t * sb;
        t = __shfl_xor(Sp1, off); Sp1 = Sp1 * sa + t * sb;
        t = __shfl_xor(Px0, off); Px0 = Px0 * sa + t * sb;
        t = __shfl_xor(Px1, off); Px1 = Px1 * sa + t * sb;
        mrun = M;
    }

    const int wave = tid >> 6, lane = tid & 63;
    if (lane == 0) {
        float* rw = redb[wave];
        rw[0]=c0; rw[1]=Sx0; rw[2]=Q0; rw[3]=mn0; rw[4]=mx0; rw[5]=Sp0; rw[6]=Px0;
        rw[7]=c1; rw[8]=Sx1; rw[9]=Q1; rw[10]=mn1; rw[11]=mx1; rw[12]=Sp1; rw[13]=Px1;
        rw[14]=mrun;
    }
    __syncthreads();

    if (tid < 2) {
        float M = redb[0][14];
        #pragma unroll
        for (int w = 1; w < 16; ++w) M = fmaxf(M, redb[w][14]);
        int base = tid * 7;
        float ck=0, Sx=0, Q=0, mnv=INFINITY, mxv=-INFINITY, Sp=0, Px=0;
        #pragma unroll
        for (int w = 0; w < 16; ++w) {
            ck += redb[w][base+0]; Sx += redb[w][base+1]; Q += redb[w][base+2];
            mnv = fminf(mnv, redb[w][base+3]); mxv = fmaxf(mxv, redb[w][base+4]);
            float e = __expf(redb[w][14] - M);
            Sp = fmaf(redb[w][base+5], e, Sp);
            Px = fmaf(redb[w][base+6], e, Px);
        }
        fin[base+0]=ck; fin[base+1]=Sx; fin[base+2]=Q;
        fin[base+3]=mnv; fin[base+4]=mxv; fin[base+5]=Sp; fin[base+6]=Px;
    }
    __syncthreads();

    if (tid < HH) {
        float sumk=0, ssqk=0, acck=0, L=0;
        float mxk=-INFINITY, mnk=INFINITY;
        #pragma unroll
        for (int r2 = 0; r2 < 2; ++r2) {
            float ck = fin[r2*7+0], Sx = fin[r2*7+1], Q = fin[r2*7+2];
            float xmn = fin[r2*7+3], xmx = fin[r2*7+4];
            float Sp = fin[r2*7+5], Px = fin[r2*7+6];
            float a = ab2[r2][tid], bb = ab2[r2][32 + tid];
            sumk += a * Sx + bb * ck;
            ssqk += a * a * Q + 2.f * a * bb * Sx + bb * bb * ck;
            acck += a * Px + bb * Sp;
            L += Sp;
            if (ck > 0.f) {
                float h1 = fmaf(a, xmn, bb), h2v = fmaf(a, xmx, bb);
                mxk = fmaxf(mxk, fmaxf(h1, h2v));
                mnk = fminf(mnk, fminf(h1, h2v));
            }
        }
        const float invN = 1.f / (float)NN;
        float mean = sumk * invN;
        float var  = fmaxf(ssqk * invN - mean * mean, 0.f);
        feat[tid]        = mean;
        feat[30 + tid]   = mxk;
        feat[60 + tid]   = mnk;
        feat[90 + tid]   = sqrtf(var);
        feat[120 + tid]  = sumk;
        feat[150 + tid]  = acck / L;
    }
    __syncthreads();

    // ---- head MLP: 180 -> 40 -> 40 -> 5 ----
    if (tid < 480) {
        int o = tid % 40, p = tid / 40;
        float z = 0.f;
        #pragma unroll
        for (int ii = 0; ii < 15; ++ii)
            z = fmaf(feat[p * 15 + ii], wf1s[(p * 15 + ii) * 40 + o], z);
        redh[p][o] = z;
    }
    __syncthreads();
    if (tid < 40) {
        float z = bf1s[tid];
        #pragma unroll
        for (int p = 0; p < 12; ++p) z += redh[p][tid];
        z1s[tid] = fmaxf(z, 0.f);
    }
    __syncthreads();
    if (tid < 40) {
        float z = bf2s[tid];
        #pragma unroll
        for (int i = 0; i < 40; ++i) z = fmaf(z1s[i], wf2s[i * 40 + tid], z);
        z2s[tid] = fmaxf(z, 0.f);
    }
    __syncthreads();
    if (tid < 5) {
        float o = bf3s[tid];
        #pragma unroll
        for (int i = 0; i < 40; ++i) o = fmaf(z2s[i], wf3s[i * 5 + tid], o);
        out[b * 5 + tid] = o;
    }
}

// ===================== Kernel B: general fallback, gated =====================
__launch_bounds__(TPBB, 1)
__global__ void pointnet_fbB(
    const float* __restrict__ x,
    const float* __restrict__ W1,  const float* __restrict__ b1,
    const float* __restrict__ W2,  const float* __restrict__ b2,
    const float* __restrict__ Wa1, const float* __restrict__ ba1,
    const float* __restrict__ Wa2, const float* __restrict__ ba2,
    const float* __restrict__ Wf1, const float* __restrict__ bf1,
    const float* __restrict__ Wf2, const float* __restrict__ bf2,
    const float* __restrict__ Wf3, const float* __restrict__ bf3,
    float* __restrict__ out, const int* __restrict__ wsflag)
{
    if (wsflag[0] == 1) return;   // fast path already produced out

    __shared__ float W2s[HH][32];
    __shared__ float Wa1s[HH][32];
    __shared__ float w1s[HH], b1s[HH], tts[HH];
    __shared__ float b2s[32], ba1s[32], Wa2s[32];
    __shared__ __align__(16) float ts_s[32];
    __shared__ int   rnk[HH];
    __shared__ __align__(16) float abt[NIV][TSTR];
    __shared__ __align__(16) float uvt[NIV][TSTR];
    __shared__ float red[8][154];
    __shared__ float feat[192];
    __shared__ float redh[12][40];
    __shared__ float z1s[40], z2s[40];
    __shared__ float wf1s[180 * 40];
    __shared__ float wf2s[40 * 40];
    __shared__ float wf3s[40 * 5];
    __shared__ float bf1s[40], bf2s[40], bf3s[8];

    const int tid = threadIdx.x;
    const int b   = blockIdx.x;

    for (int i = tid; i < HH * 32; i += TPBB) {
        int j = i >> 5, k = i & 31;
        W2s[j][k] = (k < HH) ? W2[j * HH + k] : 0.f;
    }
    for (int i = tid; i < HH * 32; i += TPBB) ((float*)Wa1s)[i] = Wa1[i];
    for (int i = tid; i < 180 * 40; i += TPBB) wf1s[i] = Wf1[i];
    for (int i = tid; i < 40 * 40;  i += TPBB) wf2s[i] = Wf2[i];
    if (tid < 40 * 5) wf3s[tid] = Wf3[tid];
    if (tid < HH) {
        float w = W1[tid], bb = b1[tid];
        w1s[tid] = w; b1s[tid] = bb;
        tts[tid] = (w != 0.f) ? (-bb / w) : INFINITY;
    }
    if (tid < 32) {
        b2s[tid]  = (tid < HH) ? b2[tid] : 0.f;
        ba1s[tid] = ba1[tid];
        Wa2s[tid] = Wa2[tid];
        ts_s[tid] = INFINITY;
    }
    if (tid < 40) { bf1s[tid] = bf1[tid]; bf2s[tid] = bf2[tid]; }
    if (tid < 5)  { bf3s[tid] = bf3[tid]; }
    const float ba2v = ba2[0];
    __syncthreads();

    if (tid < HH) {      // rank sort
        float t = tts[tid];
        int r = 0;
        for (int i = 0; i < HH; ++i) {
            float ti = tts[i];
            r += (ti < t) || (ti == t && i < tid);
        }
        ts_s[r] = t;
        rnk[tid] = r;
    }
    __syncthreads();
    for (int idx = tid; idx < NIV * 32; idx += TPBB) {
        int r = idx >> 5, k = idx & 31;
        float a = 0.f, bb = 0.f;
        if (k < HH) {
            for (int j = 0; j < HH; ++j) {
                float w = w1s[j];
                bool act = (w > 0.f) ? (rnk[j] < r)
                         : ((w < 0.f) ? (rnk[j] >= r) : (b1s[j] > 0.f));
                if (act) {
                    float w2 = W2s[j][k];
                    a  = fmaf(w,      w2, a);
                    bb = fmaf(b1s[j], w2, bb);
                }
            }
            bb += b2s[k];
        }
        abt[r][k]      = a;
        abt[r][32 + k] = bb;
    }
    __syncthreads();
    for (int idx = tid; idx < NIV * 32; idx += TPBB) {
        int r = idx >> 5, m = idx & 31;
        float u = 0.f, v = 0.f;
        for (int k = 0; k < HH; ++k) {
            float wa = Wa1s[k][m];
            u = fmaf(wa, abt[r][k],      u);
            v = fmaf(wa, abt[r][32 + k], v);
        }
        v += ba1s[m];
        uvt[r][m]      = u;
        uvt[r][32 + m] = v;
    }
    __syncthreads();

    float sum[HH], ssq[HH], mx[HH], mn[HH], acc[HH];
    #pragma unroll
    for (int k = 0; k < HH; ++k) {
        sum[k] = 0.f; ssq[k] = 0.f; acc[k] = 0.f;
        mx[k] = -INFINITY; mn[k] = INFINITY;
    }
    float mrun = -INFINITY, lrun = 0.f;
    const float* xb = x + (size_t)b * NN;
    const float4* ts4 = (const float4*)ts_s;
    const float4* wv4 = (const float4*)Wa2s;

    #pragma unroll 1
    for (int it = 0; it < NN / TPBB; ++it) {
        float xv = xb[it * TPBB + tid];
        int r = 0;
        #pragma unroll
        for (int i = 0; i < 8; ++i) {
            float4 t = ts4[i];
            r += (xv >= t.x) ? 1 : 0;
            r += (xv >= t.y) ? 1 : 0;
            r += (xv >= t.z) ? 1 : 0;
            r += (xv >= t.w) ? 1 : 0;
        }
        float h2[HH];
        const float4* arow = (const float4*)(&abt[r][0]);
        #pragma unroll
        for (int i = 0; i < 7; ++i) {
            float4 av = arow[i], bv = arow[8 + i];
            h2[4*i+0] = fmaf(xv, av.x, bv.x);
            h2[4*i+1] = fmaf(xv, av.y, bv.y);
            h2[4*i+2] = fmaf(xv, av.z, bv.z);
            h2[4*i+3] = fmaf(xv, av.w, bv.w);
        }
        { float4 av = arow[7], bv = arow[15];
          h2[28] = fmaf(xv, av.x, bv.x);
          h2[29] = fmaf(xv, av.y, bv.y); }
        #pragma unroll
        for (int k = 0; k < HH; ++k) {
            float h = h2[k];
            sum[k] += h;
            ssq[k] = fmaf(h, h, ssq[k]);
            mx[k] = fmaxf(mx[k], h);
            mn[k] = fminf(mn[k], h);
        }
        float l = ba2v;
        const float4* urow = (const float4*)(&uvt[r][0]);
        #pragma unroll
        for (int i = 0; i < 8; ++i) {
            float4 uu = urow[i], vv = urow[8 + i], ww = wv4[i];
            l = fmaf(fmaxf(fmaf(xv, uu.x, vv.x), 0.f), ww.x, l);
            l = fmaf(fmaxf(fmaf(xv, uu.y, vv.y), 0.f), ww.y, l);
            l = fmaf(fmaxf(fmaf(xv, uu.z, vv.z), 0.f), ww.z, l);
            l = fmaf(fmaxf(fmaf(xv, uu.w, vv.w), 0.f), ww.w, l);
        }
        float d = l - mrun, p;
        if (d > 8.f) {
            float s = __expf(-d);
            lrun *= s;
            #pragma unroll
            for (int k = 0; k < HH; ++k) acc[k] *= s;
            mrun = l; p = 1.f;
        } else p = __expf(d);
        lrun += p;
        #pragma unroll
        for (int k = 0; k < HH; ++k) acc[k] = fmaf(p, h2[k], acc[k]);
    }

    #pragma unroll 1
    for (int off = 32; off > 0; off >>= 1) {
        #pragma unroll
        for (int k = 0; k < HH; ++k) {
            sum[k] += __shfl_xor(sum[k], off);
            ssq[k] += __shfl_xor(ssq[k], off);
            mx[k] = fmaxf(mx[k], __shfl_xor(mx[k], off));
            mn[k] = fminf(mn[k], __shfl_xor(mn[k], off));
        }
        float mo = __shfl_xor(mrun, off);
        float lo = __shfl_xor(lrun, off);
        float M  = fmaxf(mrun, mo);
        float sa = __expf(mrun - M), sb = __expf(mo - M);
        lrun = lrun * sa + lo * sb;
        #pragma unroll
        for (int k = 0; k < HH; ++k)
            acc[k] = acc[k] * sa + __shfl_xor(acc[k], off) * sb;
        mrun = M;
    }

    const int wave = tid >> 6, lane = tid & 63;
    if (lane == 0) {
        #pragma unroll
        for (int k = 0; k < HH; ++k) {
            red[wave][k]       = sum[k];
            red[wave][30 + k]  = ssq[k];
            red[wave][60 + k]  = mx[k];
            red[wave][90 + k]  = mn[k];
            red[wave][120 + k] = acc[k];
        }
        red[wave][150] = mrun;
        red[wave][151] = lrun;
    }
    __syncthreads();

    if (tid < HH) {
        float M = -INFINITY;
        #pragma unroll
        for (int w = 0; w < 8; ++w) M = fmaxf(M, red[w][150]);
        float s = 0.f, ss = 0.f, L = 0.f, A = 0.f;
        float mxv = -INFINITY, mnv = INFINITY;
        #pragma unroll
        for (int w = 0; w < 8; ++w) {
            s  += red[w][tid];
            ss += red[w][30 + tid];
            mxv = fmaxf(mxv, red[w][60 + tid]);
            mnv = fminf(mnv, red[w][90 + tid]);
            float e = __expf(red[w][150] - M);
            L = fmaf(red[w][151], e, L);
            A = fmaf(red[w][120 + tid], e, A);
        }
        const float invN = 1.f / (float)NN;
        float mean = s * invN;
        float var  = fmaxf(ss * invN - mean * mean, 0.f);
        feat[tid]       = mean;
        feat[30 + tid]  = mxv;
        feat[60 + tid]  = mnv;
        feat[90 + tid]  = sqrtf(var);
        feat[120 + tid] = s;
        feat[150 + tid] = A / L;
    }
    __syncthreads();

    if (tid < 480) {
        int o = tid % 40, p = tid / 40;
        float z = 0.f;
        #pragma unroll
        for (int ii = 0; ii < 15; ++ii)
            z = fmaf(feat[p * 15 + ii], wf1s[(p * 15 + ii) * 40 + o], z);
        redh[p][o] = z;
    }
    __syncthreads();
    if (tid < 40) {
        float z = bf1s[tid];
        #pragma unroll
        for (int p = 0; p < 12; ++p) z += redh[p][tid];
        z1s[tid] = fmaxf(z, 0.f);
    }
    __syncthreads();
    if (tid < 40) {
        float z = bf2s[tid];
        #pragma unroll
        for (int i = 0; i < 40; ++i) z = fmaf(z1s[i], wf2s[i * 40 + tid], z);
        z2s[tid] = fmaxf(z, 0.f);
    }
    __syncthreads();
    if (tid < 5) {
        float o = bf3s[tid];
        #pragma unroll
        for (int i = 0; i < 40; ++i) o = fmaf(z2s[i], wf3s[i * 5 + tid], o);
        out[b * 5 + tid] = o;
    }
}

extern "C" void kernel_launch(void* const* d_in, const int* in_sizes, int n_in,
                              void* d_out, int out_size, void* d_ws, size_t ws_size,
                              hipStream_t stream) {
    const float* x   = (const float*)d_in[0];
    const float* W1  = (const float*)d_in[1];
    const float* b1  = (const float*)d_in[2];
    const float* W2  = (const float*)d_in[3];
    const float* b2  = (const float*)d_in[4];
    const float* Wa1 = (const float*)d_in[5];
    const float* ba1 = (const float*)d_in[6];
    const float* Wa2 = (const float*)d_in[7];
    const float* ba2 = (const float*)d_in[8];
    const float* Wf1 = (const float*)d_in[9];
    const float* bf1 = (const float*)d_in[10];
    const float* Wf2 = (const float*)d_in[11];
    const float* bf2 = (const float*)d_in[12];
    const float* Wf3 = (const float*)d_in[13];
    const float* bf3 = (const float*)d_in[14];
    float* out = (float*)d_out;
    int* wsflag = (int*)d_ws;

    pointnet_fastA<<<256, TPBA, 0, stream>>>(
        x, W1, b1, W2, b2, Wa1, ba1, Wa2, ba2,
        Wf1, bf1, Wf2, bf2, Wf3, bf3, out, wsflag);
    pointnet_fbB<<<256, TPBB, 0, stream>>>(
        x, W1, b1, W2, b2, Wa1, ba1, Wa2, ba2,
        Wf1, bf1, Wf2, bf2, Wf3, bf3, out, wsflag);
}

// Round 11
// 101.043 us; speedup vs baseline: 1.1742x; 1.0632x over previous
//
#include <hip/hip_runtime.h>
#include <math.h>

#define NN 8192
#define HH 30
#define TPBA 1024
#define TPBB 512
#define NIV 31      // coarse intervals (fallback kernel)
#define TSTR 68     // fallback table row stride (floats)

// ===================== Kernel A: Dc==1 fast path only =====================
__launch_bounds__(TPBA)
__global__ void pointnet_fastA(
    const float* __restrict__ x,
    const float* __restrict__ W1,  const float* __restrict__ b1,
    const float* __restrict__ W2,  const float* __restrict__ b2,
    const float* __restrict__ Wa1, const float* __restrict__ ba1,
    const float* __restrict__ Wa2, const float* __restrict__ ba2,
    const float* __restrict__ Wf1, const float* __restrict__ bf1,
    const float* __restrict__ Wf2, const float* __restrict__ bf2,
    const float* __restrict__ Wf3, const float* __restrict__ bf3,
    float* __restrict__ out, int* __restrict__ wsflag)
{
    __shared__ float W2s[HH][32];
    __shared__ float Wa1s[HH][32];
    __shared__ float P[HH][32];                 // W2*Wa1
    __shared__ float w1s[HH], b1s[HH], tts[HH];
    __shared__ float b2s[32], ba1s[32], Wa2s[32], vb2[32];
    __shared__ int   DcS, UnS;
    __shared__ float d0S;
    __shared__ __align__(16) float ab2[2][64];  // [a0..a31 | b0..b31]
    __shared__ __align__(16) float uv2[2][64];  // [u0..u31 | v0..v31]
    __shared__ float zz_raw[128], zz_s[128];
    __shared__ float2 gcs[129];
    __shared__ float2 gc2[2];                   // tier-U: l = g*x + c per side
    __shared__ float redb[16][16];
    __shared__ float fin[16];
    __shared__ float feat[192];
    __shared__ float redh[12][40];
    __shared__ float z1s[40], z2s[40];
    __shared__ float wf1s[180 * 40];
    __shared__ float wf2s[40 * 40];
    __shared__ float wf3s[40 * 5];
    __shared__ float bf1s[40], bf2s[40], bf3s[8];

    const int tid = threadIdx.x;
    const int b   = blockIdx.x;

    // ---- x prefetch first: HBM latency hides under the preamble ----
    float4 xl0, xl1;
    {
        const float4* xb4 = reinterpret_cast<const float4*>(x + (size_t)b * NN);
        xl0 = xb4[tid];
        xl1 = xb4[tid + TPBA];
    }

    // ---- Phase A: stage to LDS ----
    for (int i = tid; i < HH * 32; i += TPBA) {
        int j = i >> 5, k = i & 31;
        W2s[j][k] = (k < HH) ? W2[j * HH + k] : 0.f;
    }
    for (int i = tid; i < HH * 32; i += TPBA) ((float*)Wa1s)[i] = Wa1[i];
    for (int i = tid; i < 180 * 40; i += TPBA) wf1s[i] = Wf1[i];
    for (int i = tid; i < 40 * 40;  i += TPBA) wf2s[i] = Wf2[i];
    if (tid < 40 * 5) wf3s[tid] = Wf3[tid];
    if (tid < HH) {
        float w = W1[tid], bb = b1[tid];
        w1s[tid] = w; b1s[tid] = bb;
        tts[tid] = (w != 0.f) ? (-bb / w) : INFINITY;
    }
    if (tid < 32) {
        b2s[tid]  = (tid < HH) ? b2[tid] : 0.f;
        ba1s[tid] = ba1[tid];
        Wa2s[tid] = Wa2[tid];
    }
    if (tid < 40) { bf1s[tid] = bf1[tid]; bf2s[tid] = bf2[tid]; }
    if (tid < 5)  { bf3s[tid] = bf3[tid]; }
    const float ba2v = ba2[0];
    __syncthreads();

    // ---- Phase B: P, vb2 || Dc detect (wave 0) ----
    if (tid < HH * 32) {
        int j = tid >> 5, m = tid & 31;
        float s = 0.f;
        #pragma unroll
        for (int k = 0; k < HH; ++k) s = fmaf(W2s[j][k], Wa1s[k][m], s);
        P[j][m] = s;
    } else if (tid < HH * 32 + 32) {
        int m = tid - HH * 32;
        float s = 0.f;
        #pragma unroll
        for (int k = 0; k < HH; ++k) s = fmaf(Wa1s[k][m], b2s[k], s);
        vb2[m] = s;
    }
    if (tid < 64) {
        float t = (tid < HH) ? tts[tid] : INFINITY;
        bool fin_t = (t < INFINITY);
        float tmin = fin_t ? t :  INFINITY;
        float tmax = fin_t ? t : -INFINITY;
        #pragma unroll
        for (int off = 32; off > 0; off >>= 1) {
            tmin = fminf(tmin, __shfl_xor(tmin, off));
            tmax = fmaxf(tmax, __shfl_xor(tmax, off));
        }
        if (tid == 0) {
            bool dc1 = (tmin < INFINITY) && (tmin == tmax);
            DcS = dc1 ? 1 : 0;
            d0S = tmin;
        }
    }
    __syncthreads();

    if (tid == 0) wsflag[0] = DcS;   // every block writes same value: benign
    if (DcS != 1) return;            // block-uniform: kernel B will handle it

    const float d0 = d0S;
    // activity by sign: row0 (x<d0): w<0 ; row1 (x>d0): w>0 ; w==0: b1>0

    // ---- Phase C (fused): ab2 || uv2 + zz zeros || pads ----
    if (tid < 64) {
        int r = tid >> 5, k = tid & 31;
        float a = 0.f, bb = 0.f;
        if (k < HH) {
            for (int j = 0; j < HH; ++j) {
                float w = w1s[j];
                bool act = (w == 0.f) ? (b1s[j] > 0.f) : (r ? (w > 0.f) : (w < 0.f));
                if (act) {
                    float w2 = W2s[j][k];
                    a  = fmaf(w,      w2, a);
                    bb = fmaf(b1s[j], w2, bb);
                }
            }
            bb += b2s[k];
        }
        ab2[r][k]      = a;
        ab2[r][32 + k] = bb;
    } else if (tid < 128) {
        int i2 = tid - 64;
        int r = i2 >> 5, m = i2 & 31;
        float u = 0.f, v = 0.f;
        for (int j = 0; j < HH; ++j) {
            float w = w1s[j];
            bool act = (w == 0.f) ? (b1s[j] > 0.f) : (r ? (w > 0.f) : (w < 0.f));
            if (act) {
                float pj = P[j][m];
                u = fmaf(w,      pj, u);
                v = fmaf(b1s[j], pj, v);
            }
        }
        v += vb2[m] + ba1s[m];
        uv2[r][m]      = u;
        uv2[r][32 + m] = v;
        float zr = -v / u;
        bool ok = (u != 0.f) && (r == 0 ? (zr < d0) : (zr > d0));
        zz_raw[1 + i2] = ok ? zr : INFINITY;
    } else if (tid < 191) {
        zz_raw[tid - 63] = INFINITY;   // pads 65..127
    } else if (tid == 191) {
        zz_raw[0] = d0;
    }
    __syncthreads();

    // ---- tier-U detect (wave 0): all candidate zeros are INF or == d0 ----
    if (tid < 64) {
        float z = zz_raw[1 + tid];
        bool ok = !(z < INFINITY) || (z == d0);
        bool allok = __all(ok);
        if (tid == 0) UnS = allok ? 1 : 0;
    }
    __syncthreads();
    const int Un = UnS;

    if (Un) {
        // ---- tier-U: 2-entry (g,c), test points d0 -/+ 1 ----
        if (tid < 2) {
            float xm = tid ? (d0 + 1.f) : (d0 - 1.f);
            int r = tid;
            float g = 0.f, c = ba2v;
            for (int m = 0; m < 32; ++m) {
                float u = uv2[r][m], v = uv2[r][32 + m];
                if (fmaf(u, xm, v) > 0.f) {
                    float w = Wa2s[m];
                    g = fmaf(w, u, g);
                    c = fmaf(w, v, c);
                }
            }
            gc2[tid] = make_float2(g, c);
        }
        __syncthreads();
    } else {
        // ---- Phase D: stable rank sort of 128 refined breakpoints ----
        if (tid < 128) {
            float v = zz_raw[tid];
            int rk = 0;
            for (int i = 0; i < 128; ++i) {
                float vi = zz_raw[i];
                rk += (vi < v) || (vi == v && i < tid);
            }
            zz_s[rk] = v;
        }
        __syncthreads();
        // ---- Phase E: (g,c) per refined interval ----
        if (tid < 129) {
            float lo = (tid == 0)   ? -INFINITY : zz_s[tid - 1];
            float hi = (tid == 128) ?  INFINITY : zz_s[tid];
            float xm;
            if (lo == -INFINITY)      xm = (hi < INFINITY) ? hi - 1.f : 0.f;
            else if (hi == INFINITY)  xm = lo + 1.f;
            else                      xm = 0.5f * (lo + hi);
            int r = (xm >= d0) ? 1 : 0;
            float g = 0.f, c = ba2v;
            for (int m = 0; m < 32; ++m) {
                float u = uv2[r][m], v = uv2[r][32 + m];
                if (fmaf(u, xm, v) > 0.f) {
                    float w = Wa2s[m];
                    g = fmaf(w, u, g);
                    c = fmaf(w, v, c);
                }
            }
            gcs[tid] = make_float2(g, c);
        }
        __syncthreads();
    }

    // ---- main loop: 8 points/thread ----
    float c0=0,c1=0, Sx0=0,Sx1=0, Q0=0,Q1=0;
    float mn0=INFINITY,mn1=INFINITY, mx0=-INFINITY,mx1=-INFINITY;
    float Sp0=0,Sp1=0, Px0=0,Px1=0;
    float mrun = -INFINITY;

    auto upd = [&](float xv, float l, bool q1) {
        float dlt = l - mrun, p;
        if (dlt > 8.f) {                 // rare; also first point (mrun=-INF)
            float sc = __expf(-dlt);
            Sp0 *= sc; Sp1 *= sc; Px0 *= sc; Px1 *= sc;
            mrun = l; p = 1.f;
        } else p = __expf(dlt);
        float xx = xv * xv, px = p * xv;
        float i1 = q1 ? 1.f : 0.f, i0 = 1.f - i1;
        c0 += i0;                    c1 += i1;
        Sx0 = fmaf(i0, xv, Sx0);     Sx1 = fmaf(i1, xv, Sx1);
        Q0  = fmaf(i0, xx, Q0);      Q1  = fmaf(i1, xx, Q1);
        Sp0 = fmaf(i0, p,  Sp0);     Sp1 = fmaf(i1, p,  Sp1);
        Px0 = fmaf(i0, px, Px0);     Px1 = fmaf(i1, px, Px1);
        mn0 = fminf(mn0, q1 ?  INFINITY : xv);
        mx0 = fmaxf(mx0, q1 ? -INFINITY : xv);
        mn1 = fminf(mn1, q1 ? xv :  INFINITY);
        mx1 = fmaxf(mx1, q1 ? xv : -INFINITY);
    };

    float xs[8] = {xl0.x, xl0.y, xl0.z, xl0.w, xl1.x, xl1.y, xl1.z, xl1.w};

    if (Un) {
        float2 ga = gc2[0], gb = gc2[1];
        #pragma unroll
        for (int pp = 0; pp < 8; ++pp) {
            float xv = xs[pp];
            bool q1 = (xv >= d0);
            float l = fmaf(xv, q1 ? gb.x : ga.x, q1 ? gb.y : ga.y);
            upd(xv, l, q1);
        }
    } else {
        #pragma unroll
        for (int pp = 0; pp < 8; ++pp) {
            float xv = xs[pp];
            bool q1 = (xv >= d0);
            int idx = 0;
            #pragma unroll
            for (int bit = 64; bit >= 1; bit >>= 1) {
                int t = idx + bit;
                idx = (zz_s[t - 1] <= xv) ? t : idx;
            }
            float2 gc = gcs[idx];
            float l = fmaf(xv, gc.x, gc.y);
            upd(xv, l, q1);
        }
    }

    // ---- wave butterfly (15 quantities) ----
    #pragma unroll 1
    for (int off = 32; off > 0; off >>= 1) {
        c0  += __shfl_xor(c0,  off);  c1  += __shfl_xor(c1,  off);
        Sx0 += __shfl_xor(Sx0, off);  Sx1 += __shfl_xor(Sx1, off);
        Q0  += __shfl_xor(Q0,  off);  Q1  += __shfl_xor(Q1,  off);
        mn0 = fminf(mn0, __shfl_xor(mn0, off));
        mn1 = fminf(mn1, __shfl_xor(mn1, off));
        mx0 = fmaxf(mx0, __shfl_xor(mx0, off));
        mx1 = fmaxf(mx1, __shfl_xor(mx1, off));
        float mo = __shfl_xor(mrun, off);
        float M  = fmaxf(mrun, mo);
        float sa = __expf(mrun - M), sb = __expf(mo - M);
        float t;
        t = __shfl_xor(Sp0, off); Sp0 = Sp0 * sa + t * sb;
        t = __shfl_xor(Sp1, off); Sp1 = Sp1 * sa + t * sb;
        t = __shfl_xor(Px0, off); Px0 = Px0 * sa + t * sb;
        t = __shfl_xor(Px1, off); Px1 = Px1 * sa + t * sb;
        mrun = M;
    }

    const int wave = tid >> 6, lane = tid & 63;
    if (lane == 0) {
        float* rw = redb[wave];
        rw[0]=c0; rw[1]=Sx0; rw[2]=Q0; rw[3]=mn0; rw[4]=mx0; rw[5]=Sp0; rw[6]=Px0;
        rw[7]=c1; rw[8]=Sx1; rw[9]=Q1; rw[10]=mn1; rw[11]=mx1; rw[12]=Sp1; rw[13]=Px1;
        rw[14]=mrun;
    }
    __syncthreads();

    if (tid < 2) {
        float M = redb[0][14];
        #pragma unroll
        for (int w = 1; w < 16; ++w) M = fmaxf(M, redb[w][14]);
        int base = tid * 7;
        float ck=0, Sx=0, Q=0, mnv=INFINITY, mxv=-INFINITY, Sp=0, Px=0;
        #pragma unroll
        for (int w = 0; w < 16; ++w) {
            ck += redb[w][base+0]; Sx += redb[w][base+1]; Q += redb[w][base+2];
            mnv = fminf(mnv, redb[w][base+3]); mxv = fmaxf(mxv, redb[w][base+4]);
            float e = __expf(redb[w][14] - M);
            Sp = fmaf(redb[w][base+5], e, Sp);
            Px = fmaf(redb[w][base+6], e, Px);
        }
        fin[base+0]=ck; fin[base+1]=Sx; fin[base+2]=Q;
        fin[base+3]=mnv; fin[base+4]=mxv; fin[base+5]=Sp; fin[base+6]=Px;
    }
    __syncthreads();

    if (tid < HH) {
        float sumk=0, ssqk=0, acck=0, L=0;
        float mxk=-INFINITY, mnk=INFINITY;
        #pragma unroll
        for (int r2 = 0; r2 < 2; ++r2) {
            float ck = fin[r2*7+0], Sx = fin[r2*7+1], Q = fin[r2*7+2];
            float xmn = fin[r2*7+3], xmx = fin[r2*7+4];
            float Sp = fin[r2*7+5], Px = fin[r2*7+6];
            float a = ab2[r2][tid], bb = ab2[r2][32 + tid];
            sumk += a * Sx + bb * ck;
            ssqk += a * a * Q + 2.f * a * bb * Sx + bb * bb * ck;
            acck += a * Px + bb * Sp;
            L += Sp;
            if (ck > 0.f) {
                float h1 = fmaf(a, xmn, bb), h2v = fmaf(a, xmx, bb);
                mxk = fmaxf(mxk, fmaxf(h1, h2v));
                mnk = fminf(mnk, fminf(h1, h2v));
            }
        }
        const float invN = 1.f / (float)NN;
        float mean = sumk * invN;
        float var  = fmaxf(ssqk * invN - mean * mean, 0.f);
        feat[tid]        = mean;
        feat[30 + tid]   = mxk;
        feat[60 + tid]   = mnk;
        feat[90 + tid]   = sqrtf(var);
        feat[120 + tid]  = sumk;
        feat[150 + tid]  = acck / L;
    }
    __syncthreads();

    // ---- head MLP: 180 -> 40 -> 40 -> 5 ----
    if (tid < 480) {
        int o = tid % 40, p = tid / 40;
        float z = 0.f;
        #pragma unroll
        for (int ii = 0; ii < 15; ++ii)
            z = fmaf(feat[p * 15 + ii], wf1s[(p * 15 + ii) * 40 + o], z);
        redh[p][o] = z;
    }
    __syncthreads();
    if (tid < 40) {
        float z = bf1s[tid];
        #pragma unroll
        for (int p = 0; p < 12; ++p) z += redh[p][tid];
        z1s[tid] = fmaxf(z, 0.f);
    }
    __syncthreads();
    if (tid < 40) {
        float z = bf2s[tid];
        #pragma unroll
        for (int i = 0; i < 40; ++i) z = fmaf(z1s[i], wf2s[i * 40 + tid], z);
        z2s[tid] = fmaxf(z, 0.f);
    }
    __syncthreads();
    if (tid < 5) {
        float o = bf3s[tid];
        #pragma unroll
        for (int i = 0; i < 40; ++i) o = fmaf(z2s[i], wf3s[i * 5 + tid], o);
        out[b * 5 + tid] = o;
    }
}

// ===================== Kernel B: general fallback, gated =====================
__launch_bounds__(TPBB, 1)
__global__ void pointnet_fbB(
    const float* __restrict__ x,
    const float* __restrict__ W1,  const float* __restrict__ b1,
    const float* __restrict__ W2,  const float* __restrict__ b2,
    const float* __restrict__ Wa1, const float* __restrict__ ba1,
    const float* __restrict__ Wa2, const float* __restrict__ ba2,
    const float* __restrict__ Wf1, const float* __restrict__ bf1,
    const float* __restrict__ Wf2, const float* __restrict__ bf2,
    const float* __restrict__ Wf3, const float* __restrict__ bf3,
    float* __restrict__ out, const int* __restrict__ wsflag)
{
    if (wsflag[0] == 1) return;   // fast path already produced out

    __shared__ float W2s[HH][32];
    __shared__ float Wa1s[HH][32];
    __shared__ float w1s[HH], b1s[HH], tts[HH];
    __shared__ float b2s[32], ba1s[32], Wa2s[32];
    __shared__ __align__(16) float ts_s[32];
    __shared__ int   rnk[HH];
    __shared__ __align__(16) float abt[NIV][TSTR];
    __shared__ __align__(16) float uvt[NIV][TSTR];
    __shared__ float red[8][154];
    __shared__ float feat[192];
    __shared__ float redh[12][40];
    __shared__ float z1s[40], z2s[40];
    __shared__ float wf1s[180 * 40];
    __shared__ float wf2s[40 * 40];
    __shared__ float wf3s[40 * 5];
    __shared__ float bf1s[40], bf2s[40], bf3s[8];

    const int tid = threadIdx.x;
    const int b   = blockIdx.x;

    for (int i = tid; i < HH * 32; i += TPBB) {
        int j = i >> 5, k = i & 31;
        W2s[j][k] = (k < HH) ? W2[j * HH + k] : 0.f;
    }
    for (int i = tid; i < HH * 32; i += TPBB) ((float*)Wa1s)[i] = Wa1[i];
    for (int i = tid; i < 180 * 40; i += TPBB) wf1s[i] = Wf1[i];
    for (int i = tid; i < 40 * 40;  i += TPBB) wf2s[i] = Wf2[i];
    if (tid < 40 * 5) wf3s[tid] = Wf3[tid];
    if (tid < HH) {
        float w = W1[tid], bb = b1[tid];
        w1s[tid] = w; b1s[tid] = bb;
        tts[tid] = (w != 0.f) ? (-bb / w) : INFINITY;
    }
    if (tid < 32) {
        b2s[tid]  = (tid < HH) ? b2[tid] : 0.f;
        ba1s[tid] = ba1[tid];
        Wa2s[tid] = Wa2[tid];
        ts_s[tid] = INFINITY;
    }
    if (tid < 40) { bf1s[tid] = bf1[tid]; bf2s[tid] = bf2[tid]; }
    if (tid < 5)  { bf3s[tid] = bf3[tid]; }
    const float ba2v = ba2[0];
    __syncthreads();

    if (tid < HH) {      // rank sort
        float t = tts[tid];
        int r = 0;
        for (int i = 0; i < HH; ++i) {
            float ti = tts[i];
            r += (ti < t) || (ti == t && i < tid);
        }
        ts_s[r] = t;
        rnk[tid] = r;
    }
    __syncthreads();
    for (int idx = tid; idx < NIV * 32; idx += TPBB) {
        int r = idx >> 5, k = idx & 31;
        float a = 0.f, bb = 0.f;
        if (k < HH) {
            for (int j = 0; j < HH; ++j) {
                float w = w1s[j];
                bool act = (w > 0.f) ? (rnk[j] < r)
                         : ((w < 0.f) ? (rnk[j] >= r) : (b1s[j] > 0.f));
                if (act) {
                    float w2 = W2s[j][k];
                    a  = fmaf(w,      w2, a);
                    bb = fmaf(b1s[j], w2, bb);
                }
            }
            bb += b2s[k];
        }
        abt[r][k]      = a;
        abt[r][32 + k] = bb;
    }
    __syncthreads();
    for (int idx = tid; idx < NIV * 32; idx += TPBB) {
        int r = idx >> 5, m = idx & 31;
        float u = 0.f, v = 0.f;
        for (int k = 0; k < HH; ++k) {
            float wa = Wa1s[k][m];
            u = fmaf(wa, abt[r][k],      u);
            v = fmaf(wa, abt[r][32 + k], v);
        }
        v += ba1s[m];
        uvt[r][m]      = u;
        uvt[r][32 + m] = v;
    }
    __syncthreads();

    float sum[HH], ssq[HH], mx[HH], mn[HH], acc[HH];
    #pragma unroll
    for (int k = 0; k < HH; ++k) {
        sum[k] = 0.f; ssq[k] = 0.f; acc[k] = 0.f;
        mx[k] = -INFINITY; mn[k] = INFINITY;
    }
    float mrun = -INFINITY, lrun = 0.f;
    const float* xb = x + (size_t)b * NN;
    const float4* ts4 = (const float4*)ts_s;
    const float4* wv4 = (const float4*)Wa2s;

    #pragma unroll 1
    for (int it = 0; it < NN / TPBB; ++it) {
        float xv = xb[it * TPBB + tid];
        int r = 0;
        #pragma unroll
        for (int i = 0; i < 8; ++i) {
            float4 t = ts4[i];
            r += (xv >= t.x) ? 1 : 0;
            r += (xv >= t.y) ? 1 : 0;
            r += (xv >= t.z) ? 1 : 0;
            r += (xv >= t.w) ? 1 : 0;
        }
        float h2[HH];
        const float4* arow = (const float4*)(&abt[r][0]);
        #pragma unroll
        for (int i = 0; i < 7; ++i) {
            float4 av = arow[i], bv = arow[8 + i];
            h2[4*i+0] = fmaf(xv, av.x, bv.x);
            h2[4*i+1] = fmaf(xv, av.y, bv.y);
            h2[4*i+2] = fmaf(xv, av.z, bv.z);
            h2[4*i+3] = fmaf(xv, av.w, bv.w);
        }
        { float4 av = arow[7], bv = arow[15];
          h2[28] = fmaf(xv, av.x, bv.x);
          h2[29] = fmaf(xv, av.y, bv.y); }
        #pragma unroll
        for (int k = 0; k < HH; ++k) {
            float h = h2[k];
            sum[k] += h;
            ssq[k] = fmaf(h, h, ssq[k]);
            mx[k] = fmaxf(mx[k], h);
            mn[k] = fminf(mn[k], h);
        }
        float l = ba2v;
        const float4* urow = (const float4*)(&uvt[r][0]);
        #pragma unroll
        for (int i = 0; i < 8; ++i) {
            float4 uu = urow[i], vv = urow[8 + i], ww = wv4[i];
            l = fmaf(fmaxf(fmaf(xv, uu.x, vv.x), 0.f), ww.x, l);
            l = fmaf(fmaxf(fmaf(xv, uu.y, vv.y), 0.f), ww.y, l);
            l = fmaf(fmaxf(fmaf(xv, uu.z, vv.z), 0.f), ww.z, l);
            l = fmaf(fmaxf(fmaf(xv, uu.w, vv.w), 0.f), ww.w, l);
        }
        float d = l - mrun, p;
        if (d > 8.f) {
            float s = __expf(-d);
            lrun *= s;
            #pragma unroll
            for (int k = 0; k < HH; ++k) acc[k] *= s;
            mrun = l; p = 1.f;
        } else p = __expf(d);
        lrun += p;
        #pragma unroll
        for (int k = 0; k < HH; ++k) acc[k] = fmaf(p, h2[k], acc[k]);
    }

    #pragma unroll 1
    for (int off = 32; off > 0; off >>= 1) {
        #pragma unroll
        for (int k = 0; k < HH; ++k) {
            sum[k] += __shfl_xor(sum[k], off);
            ssq[k] += __shfl_xor(ssq[k], off);
            mx[k] = fmaxf(mx[k], __shfl_xor(mx[k], off));
            mn[k] = fminf(mn[k], __shfl_xor(mn[k], off));
        }
        float mo = __shfl_xor(mrun, off);
        float lo = __shfl_xor(lrun, off);
        float M  = fmaxf(mrun, mo);
        float sa = __expf(mrun - M), sb = __expf(mo - M);
        lrun = lrun * sa + lo * sb;
        #pragma unroll
        for (int k = 0; k < HH; ++k)
            acc[k] = acc[k] * sa + __shfl_xor(acc[k], off) * sb;
        mrun = M;
    }

    const int wave = tid >> 6, lane = tid & 63;
    if (lane == 0) {
        #pragma unroll
        for (int k = 0; k < HH; ++k) {
            red[wave][k]       = sum[k];
            red[wave][30 + k]  = ssq[k];
            red[wave][60 + k]  = mx[k];
            red[wave][90 + k]  = mn[k];
            red[wave][120 + k] = acc[k];
        }
        red[wave][150] = mrun;
        red[wave][151] = lrun;
    }
    __syncthreads();

    if (tid < HH) {
        float M = -INFINITY;
        #pragma unroll
        for (int w = 0; w < 8; ++w) M = fmaxf(M, red[w][150]);
        float s = 0.f, ss = 0.f, L = 0.f, A = 0.f;
        float mxv = -INFINITY, mnv = INFINITY;
        #pragma unroll
        for (int w = 0; w < 8; ++w) {
            s  += red[w][tid];
            ss += red[w][30 + tid];
            mxv = fmaxf(mxv, red[w][60 + tid]);
            mnv = fminf(mnv, red[w][90 + tid]);
            float e = __expf(red[w][150] - M);
            L = fmaf(red[w][151], e, L);
            A = fmaf(red[w][120 + tid], e, A);
        }
        const float invN = 1.f / (float)NN;
        float mean = s * invN;
        float var  = fmaxf(ss * invN - mean * mean, 0.f);
        feat[tid]       = mean;
        feat[30 + tid]  = mxv;
        feat[60 + tid]  = mnv;
        feat[90 + tid]  = sqrtf(var);
        feat[120 + tid] = s;
        feat[150 + tid] = A / L;
    }
    __syncthreads();

    if (tid < 480) {
        int o = tid % 40, p = tid / 40;
        float z = 0.f;
        #pragma unroll
        for (int ii = 0; ii < 15; ++ii)
            z = fmaf(feat[p * 15 + ii], wf1s[(p * 15 + ii) * 40 + o], z);
        redh[p][o] = z;
    }
    __syncthreads();
    if (tid < 40) {
        float z = bf1s[tid];
        #pragma unroll
        for (int p = 0; p < 12; ++p) z += redh[p][tid];
        z1s[tid] = fmaxf(z, 0.f);
    }
    __syncthreads();
    if (tid < 40) {
        float z = bf2s[tid];
        #pragma unroll
        for (int i = 0; i < 40; ++i) z = fmaf(z1s[i], wf2s[i * 40 + tid], z);
        z2s[tid] = fmaxf(z, 0.f);
    }
    __syncthreads();
    if (tid < 5) {
        float o = bf3s[tid];
        #pragma unroll
        for (int i = 0; i < 40; ++i) o = fmaf(z2s[i], wf3s[i * 5 + tid], o);
        out[b * 5 + tid] = o;
    }
}

extern "C" void kernel_launch(void* const* d_in, const int* in_sizes, int n_in,
                              void* d_out, int out_size, void* d_ws, size_t ws_size,
                              hipStream_t stream) {
    const float* x   = (const float*)d_in[0];
    const float* W1  = (const float*)d_in[1];
    const float* b1  = (const float*)d_in[2];
    const float* W2  = (const float*)d_in[3];
    const float* b2  = (const float*)d_in[4];
    const float* Wa1 = (const float*)d_in[5];
    const float* ba1 = (const float*)d_in[6];
    const float* Wa2 = (const float*)d_in[7];
    const float* ba2 = (const float*)d_in[8];
    const float* Wf1 = (const float*)d_in[9];
    const float* bf1 = (const float*)d_in[10];
    const float* Wf2 = (const float*)d_in[11];
    const float* bf2 = (const float*)d_in[12];
    const float* Wf3 = (const float*)d_in[13];
    const float* bf3 = (const float*)d_in[14];
    float* out = (float*)d_out;
    int* wsflag = (int*)d_ws;

    pointnet_fastA<<<256, TPBA, 0, stream>>>(
        x, W1, b1, W2, b2, Wa1, ba1, Wa2, ba2,
        Wf1, bf1, Wf2, bf2, Wf3, bf3, out, wsflag);
    pointnet_fbB<<<256, TPBB, 0, stream>>>(
        x, W1, b1, W2, b2, Wa1, ba1, Wa2, ba2,
        Wf1, bf1, Wf2, bf2, Wf3, bf3, out, wsflag);
}

// Round 12
// 99.227 us; speedup vs baseline: 1.1957x; 1.0183x over previous
//
#include <hip/hip_runtime.h>
#include <math.h>

#define NN 8192
#define HH 30
#define TPBA 1024
#define TPBB 512
#define NIV 31      // coarse intervals (fallback kernel)
#define TSTR 68     // fallback table row stride (floats)

// ===================== Kernel A: Dc==1 fast path only =====================
__launch_bounds__(TPBA)
__global__ void pointnet_fastA(
    const float* __restrict__ x,
    const float* __restrict__ W1,  const float* __restrict__ b1,
    const float* __restrict__ W2,  const float* __restrict__ b2,
    const float* __restrict__ Wa1, const float* __restrict__ ba1,
    const float* __restrict__ Wa2, const float* __restrict__ ba2,
    const float* __restrict__ Wf1, const float* __restrict__ bf1,
    const float* __restrict__ Wf2, const float* __restrict__ bf2,
    const float* __restrict__ Wf3, const float* __restrict__ bf3,
    float* __restrict__ out, int* __restrict__ wsflag)
{
    __shared__ float W2s[HH][32];
    __shared__ float Wa1s[HH][32];
    __shared__ float P[HH][32];                 // W2*Wa1
    __shared__ float w1s[HH], b1s[HH], tts[HH];
    __shared__ float b2s[32], ba1s[32], Wa2s[32], vb2[32];
    __shared__ int   DcS, UnS;
    __shared__ float d0S;
    __shared__ __align__(16) float ab2[2][64];  // [a0..a31 | b0..b31]
    __shared__ __align__(16) float uv2[2][64];  // [u0..u31 | v0..v31]
    __shared__ float zz_raw[128], zz_s[128];
    __shared__ float2 gcs[129];
    __shared__ float2 gc2[2];                   // tier-U: l = g*x + c per side
    __shared__ float redb[16][16];
    __shared__ float fin[16];
    __shared__ float feat[192];
    __shared__ float redh[12][40];
    __shared__ float z1s[40], z2s[40];

    const int tid = threadIdx.x;
    const int b   = blockIdx.x;

    // ---- x prefetch first: HBM latency hides under the preamble ----
    float4 xl0, xl1;
    {
        const float4* xb4 = reinterpret_cast<const float4*>(x + (size_t)b * NN);
        xl0 = xb4[tid];
        xl1 = xb4[tid + TPBA];
    }

    // ---- Phase A: stage small weights to LDS (head-MLP weights stay in global) ----
    for (int i = tid; i < HH * 32; i += TPBA) {
        int j = i >> 5, k = i & 31;
        W2s[j][k] = (k < HH) ? W2[j * HH + k] : 0.f;
    }
    for (int i = tid; i < HH * 32; i += TPBA) ((float*)Wa1s)[i] = Wa1[i];
    if (tid < HH) {
        float w = W1[tid], bb = b1[tid];
        w1s[tid] = w; b1s[tid] = bb;
        tts[tid] = (w != 0.f) ? (-bb / w) : INFINITY;
    }
    if (tid < 32) {
        b2s[tid]  = (tid < HH) ? b2[tid] : 0.f;
        ba1s[tid] = ba1[tid];
        Wa2s[tid] = Wa2[tid];
    }
    const float ba2v = ba2[0];
    __syncthreads();

    // ---- Phase B: P, vb2 || Dc detect (wave 0) ----
    if (tid < HH * 32) {
        int j = tid >> 5, m = tid & 31;
        float s = 0.f;
        #pragma unroll
        for (int k = 0; k < HH; ++k) s = fmaf(W2s[j][k], Wa1s[k][m], s);
        P[j][m] = s;
    } else if (tid < HH * 32 + 32) {
        int m = tid - HH * 32;
        float s = 0.f;
        #pragma unroll
        for (int k = 0; k < HH; ++k) s = fmaf(Wa1s[k][m], b2s[k], s);
        vb2[m] = s;
    }
    if (tid < 64) {
        float t = (tid < HH) ? tts[tid] : INFINITY;
        bool fin_t = (t < INFINITY);
        float tmin = fin_t ? t :  INFINITY;
        float tmax = fin_t ? t : -INFINITY;
        #pragma unroll
        for (int off = 32; off > 0; off >>= 1) {
            tmin = fminf(tmin, __shfl_xor(tmin, off));
            tmax = fmaxf(tmax, __shfl_xor(tmax, off));
        }
        if (tid == 0) {
            bool dc1 = (tmin < INFINITY) && (tmin == tmax);
            DcS = dc1 ? 1 : 0;
            d0S = tmin;
        }
    }
    __syncthreads();

    if (tid == 0) wsflag[0] = DcS;   // every block writes same value: benign
    if (DcS != 1) return;            // block-uniform: kernel B will handle it

    const float d0 = d0S;
    // activity by sign: row0 (x<d0): w<0 ; row1 (x>d0): w>0 ; w==0: b1>0

    // ---- Phase C (fused): ab2 (wave0) || uv2 + zz zeros + tier-U detect (wave1) || pads ----
    if (tid < 64) {
        int r = tid >> 5, k = tid & 31;
        float a = 0.f, bb = 0.f;
        if (k < HH) {
            for (int j = 0; j < HH; ++j) {
                float w = w1s[j];
                bool act = (w == 0.f) ? (b1s[j] > 0.f) : (r ? (w > 0.f) : (w < 0.f));
                if (act) {
                    float w2 = W2s[j][k];
                    a  = fmaf(w,      w2, a);
                    bb = fmaf(b1s[j], w2, bb);
                }
            }
            bb += b2s[k];
        }
        ab2[r][k]      = a;
        ab2[r][32 + k] = bb;
    } else if (tid < 128) {
        int i2 = tid - 64;
        int r = i2 >> 5, m = i2 & 31;
        float u = 0.f, v = 0.f;
        for (int j = 0; j < HH; ++j) {
            float w = w1s[j];
            bool act = (w == 0.f) ? (b1s[j] > 0.f) : (r ? (w > 0.f) : (w < 0.f));
            if (act) {
                float pj = P[j][m];
                u = fmaf(w,      pj, u);
                v = fmaf(b1s[j], pj, v);
            }
        }
        v += vb2[m] + ba1s[m];
        uv2[r][m]      = u;
        uv2[r][32 + m] = v;
        float zr = -v / u;
        bool okr = (u != 0.f) && (r == 0 ? (zr < d0) : (zr > d0));
        float zs = okr ? zr : INFINITY;
        zz_raw[1 + i2] = zs;
        // tier-U detect entirely within wave 1 (tids 64..127 = exactly one wave)
        bool tu = !(zs < INFINITY) || (zs == d0);
        bool allok = __all(tu);
        if (i2 == 0) UnS = allok ? 1 : 0;
    } else if (tid < 191) {
        zz_raw[tid - 63] = INFINITY;   // pads 65..127
    } else if (tid == 191) {
        zz_raw[0] = d0;
    }
    __syncthreads();
    const int Un = UnS;

    if (Un) {
        // ---- tier-U: 2-entry (g,c), test points d0 -/+ 1 ----
        if (tid < 2) {
            float xm = tid ? (d0 + 1.f) : (d0 - 1.f);
            int r = tid;
            float g = 0.f, c = ba2v;
            for (int m = 0; m < 32; ++m) {
                float u = uv2[r][m], v = uv2[r][32 + m];
                if (fmaf(u, xm, v) > 0.f) {
                    float w = Wa2s[m];
                    g = fmaf(w, u, g);
                    c = fmaf(w, v, c);
                }
            }
            gc2[tid] = make_float2(g, c);
        }
        __syncthreads();
    } else {
        // ---- Phase D: stable rank sort of 128 refined breakpoints ----
        if (tid < 128) {
            float v = zz_raw[tid];
            int rk = 0;
            for (int i = 0; i < 128; ++i) {
                float vi = zz_raw[i];
                rk += (vi < v) || (vi == v && i < tid);
            }
            zz_s[rk] = v;
        }
        __syncthreads();
        // ---- Phase E: (g,c) per refined interval ----
        if (tid < 129) {
            float lo = (tid == 0)   ? -INFINITY : zz_s[tid - 1];
            float hi = (tid == 128) ?  INFINITY : zz_s[tid];
            float xm;
            if (lo == -INFINITY)      xm = (hi < INFINITY) ? hi - 1.f : 0.f;
            else if (hi == INFINITY)  xm = lo + 1.f;
            else                      xm = 0.5f * (lo + hi);
            int r = (xm >= d0) ? 1 : 0;
            float g = 0.f, c = ba2v;
            for (int m = 0; m < 32; ++m) {
                float u = uv2[r][m], v = uv2[r][32 + m];
                if (fmaf(u, xm, v) > 0.f) {
                    float w = Wa2s[m];
                    g = fmaf(w, u, g);
                    c = fmaf(w, v, c);
                }
            }
            gcs[tid] = make_float2(g, c);
        }
        __syncthreads();
    }

    // ---- main loop: 8 points/thread ----
    float c0=0,c1=0, Sx0=0,Sx1=0, Q0=0,Q1=0;
    float mn0=INFINITY,mn1=INFINITY, mx0=-INFINITY,mx1=-INFINITY;
    float Sp0=0,Sp1=0, Px0=0,Px1=0;
    float mrun = -INFINITY;

    auto upd = [&](float xv, float l, bool q1) {
        float dlt = l - mrun, p;
        if (dlt > 8.f) {                 // rare; also first point (mrun=-INF)
            float sc = __expf(-dlt);
            Sp0 *= sc; Sp1 *= sc; Px0 *= sc; Px1 *= sc;
            mrun = l; p = 1.f;
        } else p = __expf(dlt);
        float xx = xv * xv, px = p * xv;
        float i1 = q1 ? 1.f : 0.f, i0 = 1.f - i1;
        c0 += i0;                    c1 += i1;
        Sx0 = fmaf(i0, xv, Sx0);     Sx1 = fmaf(i1, xv, Sx1);
        Q0  = fmaf(i0, xx, Q0);      Q1  = fmaf(i1, xx, Q1);
        Sp0 = fmaf(i0, p,  Sp0);     Sp1 = fmaf(i1, p,  Sp1);
        Px0 = fmaf(i0, px, Px0);     Px1 = fmaf(i1, px, Px1);
        mn0 = fminf(mn0, q1 ?  INFINITY : xv);
        mx0 = fmaxf(mx0, q1 ? -INFINITY : xv);
        mn1 = fminf(mn1, q1 ? xv :  INFINITY);
        mx1 = fmaxf(mx1, q1 ? xv : -INFINITY);
    };

    float xs[8] = {xl0.x, xl0.y, xl0.z, xl0.w, xl1.x, xl1.y, xl1.z, xl1.w};

    if (Un) {
        float2 ga = gc2[0], gb = gc2[1];
        #pragma unroll
        for (int pp = 0; pp < 8; ++pp) {
            float xv = xs[pp];
            bool q1 = (xv >= d0);
            float l = fmaf(xv, q1 ? gb.x : ga.x, q1 ? gb.y : ga.y);
            upd(xv, l, q1);
        }
    } else {
        #pragma unroll
        for (int pp = 0; pp < 8; ++pp) {
            float xv = xs[pp];
            bool q1 = (xv >= d0);
            int idx = 0;
            #pragma unroll
            for (int bit = 64; bit >= 1; bit >>= 1) {
                int t = idx + bit;
                idx = (zz_s[t - 1] <= xv) ? t : idx;
            }
            float2 gc = gcs[idx];
            float l = fmaf(xv, gc.x, gc.y);
            upd(xv, l, q1);
        }
    }

    // ---- wave butterfly (15 quantities) ----
    #pragma unroll 1
    for (int off = 32; off > 0; off >>= 1) {
        c0  += __shfl_xor(c0,  off);  c1  += __shfl_xor(c1,  off);
        Sx0 += __shfl_xor(Sx0, off);  Sx1 += __shfl_xor(Sx1, off);
        Q0  += __shfl_xor(Q0,  off);  Q1  += __shfl_xor(Q1,  off);
        mn0 = fminf(mn0, __shfl_xor(mn0, off));
        mn1 = fminf(mn1, __shfl_xor(mn1, off));
        mx0 = fmaxf(mx0, __shfl_xor(mx0, off));
        mx1 = fmaxf(mx1, __shfl_xor(mx1, off));
        float mo = __shfl_xor(mrun, off);
        float M  = fmaxf(mrun, mo);
        float sa = __expf(mrun - M), sb = __expf(mo - M);
        float t;
        t = __shfl_xor(Sp0, off); Sp0 = Sp0 * sa + t * sb;
        t = __shfl_xor(Sp1, off); Sp1 = Sp1 * sa + t * sb;
        t = __shfl_xor(Px0, off); Px0 = Px0 * sa + t * sb;
        t = __shfl_xor(Px1, off); Px1 = Px1 * sa + t * sb;
        mrun = M;
    }

    const int wave = tid >> 6, lane = tid & 63;
    if (lane == 0) {
        float* rw = redb[wave];
        rw[0]=c0; rw[1]=Sx0; rw[2]=Q0; rw[3]=mn0; rw[4]=mx0; rw[5]=Sp0; rw[6]=Px0;
        rw[7]=c1; rw[8]=Sx1; rw[9]=Q1; rw[10]=mn1; rw[11]=mx1; rw[12]=Sp1; rw[13]=Px1;
        rw[14]=mrun;
    }
    __syncthreads();

    if (tid < 2) {
        float M = redb[0][14];
        #pragma unroll
        for (int w = 1; w < 16; ++w) M = fmaxf(M, redb[w][14]);
        int base = tid * 7;
        float ck=0, Sx=0, Q=0, mnv=INFINITY, mxv=-INFINITY, Sp=0, Px=0;
        #pragma unroll
        for (int w = 0; w < 16; ++w) {
            ck += redb[w][base+0]; Sx += redb[w][base+1]; Q += redb[w][base+2];
            mnv = fminf(mnv, redb[w][base+3]); mxv = fmaxf(mxv, redb[w][base+4]);
            float e = __expf(redb[w][14] - M);
            Sp = fmaf(redb[w][base+5], e, Sp);
            Px = fmaf(redb[w][base+6], e, Px);
        }
        fin[base+0]=ck; fin[base+1]=Sx; fin[base+2]=Q;
        fin[base+3]=mnv; fin[base+4]=mxv; fin[base+5]=Sp; fin[base+6]=Px;
    }
    __syncthreads();

    if (tid < HH) {
        float sumk=0, ssqk=0, acck=0, L=0;
        float mxk=-INFINITY, mnk=INFINITY;
        #pragma unroll
        for (int r2 = 0; r2 < 2; ++r2) {
            float ck = fin[r2*7+0], Sx = fin[r2*7+1], Q = fin[r2*7+2];
            float xmn = fin[r2*7+3], xmx = fin[r2*7+4];
            float Sp = fin[r2*7+5], Px = fin[r2*7+6];
            float a = ab2[r2][tid], bb = ab2[r2][32 + tid];
            sumk += a * Sx + bb * ck;
            ssqk += a * a * Q + 2.f * a * bb * Sx + bb * bb * ck;
            acck += a * Px + bb * Sp;
            L += Sp;
            if (ck > 0.f) {
                float h1 = fmaf(a, xmn, bb), h2v = fmaf(a, xmx, bb);
                mxk = fmaxf(mxk, fmaxf(h1, h2v));
                mnk = fminf(mnk, fminf(h1, h2v));
            }
        }
        const float invN = 1.f / (float)NN;
        float mean = sumk * invN;
        float var  = fmaxf(ssqk * invN - mean * mean, 0.f);
        feat[tid]        = mean;
        feat[30 + tid]   = mxk;
        feat[60 + tid]   = mnk;
        feat[90 + tid]   = sqrtf(var);
        feat[120 + tid]  = sumk;
        feat[150 + tid]  = acck / L;
    }
    __syncthreads();

    // ---- head MLP: 180 -> 40 -> 40 -> 5 (weights straight from global) ----
    if (tid < 480) {
        int o = tid % 40, p = tid / 40;
        const float* wrow = Wf1 + (p * 15) * 40 + o;
        float z = 0.f;
        #pragma unroll
        for (int ii = 0; ii < 15; ++ii)
            z = fmaf(feat[p * 15 + ii], wrow[ii * 40], z);
        redh[p][o] = z;
    }
    __syncthreads();
    if (tid < 40) {
        float z = bf1[tid];
        #pragma unroll
        for (int p = 0; p < 12; ++p) z += redh[p][tid];
        z1s[tid] = fmaxf(z, 0.f);
    }
    __syncthreads();
    if (tid < 40) {
        float z = bf2[tid];
        #pragma unroll
        for (int i = 0; i < 40; ++i) z = fmaf(z1s[i], Wf2[i * 40 + tid], z);
        z2s[tid] = fmaxf(z, 0.f);
    }
    __syncthreads();
    if (tid < 5) {
        float o = bf3[tid];
        #pragma unroll
        for (int i = 0; i < 40; ++i) o = fmaf(z2s[i], Wf3[i * 5 + tid], o);
        out[b * 5 + tid] = o;
    }
}

// ===================== Kernel B: general fallback, gated =====================
__launch_bounds__(TPBB, 1)
__global__ void pointnet_fbB(
    const float* __restrict__ x,
    const float* __restrict__ W1,  const float* __restrict__ b1,
    const float* __restrict__ W2,  const float* __restrict__ b2,
    const float* __restrict__ Wa1, const float* __restrict__ ba1,
    const float* __restrict__ Wa2, const float* __restrict__ ba2,
    const float* __restrict__ Wf1, const float* __restrict__ bf1,
    const float* __restrict__ Wf2, const float* __restrict__ bf2,
    const float* __restrict__ Wf3, const float* __restrict__ bf3,
    float* __restrict__ out, const int* __restrict__ wsflag)
{
    if (wsflag[0] == 1) return;   // fast path already produced out

    __shared__ float W2s[HH][32];
    __shared__ float Wa1s[HH][32];
    __shared__ float w1s[HH], b1s[HH], tts[HH];
    __shared__ float b2s[32], ba1s[32], Wa2s[32];
    __shared__ __align__(16) float ts_s[32];
    __shared__ int   rnk[HH];
    __shared__ __align__(16) float abt[NIV][TSTR];
    __shared__ __align__(16) float uvt[NIV][TSTR];
    __shared__ float red[8][154];
    __shared__ float feat[192];
    __shared__ float redh[12][40];
    __shared__ float z1s[40], z2s[40];
    __shared__ float wf1s[180 * 40];
    __shared__ float wf2s[40 * 40];
    __shared__ float wf3s[40 * 5];
    __shared__ float bf1s[40], bf2s[40], bf3s[8];

    const int tid = threadIdx.x;
    const int b   = blockIdx.x;

    for (int i = tid; i < HH * 32; i += TPBB) {
        int j = i >> 5, k = i & 31;
        W2s[j][k] = (k < HH) ? W2[j * HH + k] : 0.f;
    }
    for (int i = tid; i < HH * 32; i += TPBB) ((float*)Wa1s)[i] = Wa1[i];
    for (int i = tid; i < 180 * 40; i += TPBB) wf1s[i] = Wf1[i];
    for (int i = tid; i < 40 * 40;  i += TPBB) wf2s[i] = Wf2[i];
    if (tid < 40 * 5) wf3s[tid] = Wf3[tid];
    if (tid < HH) {
        float w = W1[tid], bb = b1[tid];
        w1s[tid] = w; b1s[tid] = bb;
        tts[tid] = (w != 0.f) ? (-bb / w) : INFINITY;
    }
    if (tid < 32) {
        b2s[tid]  = (tid < HH) ? b2[tid] : 0.f;
        ba1s[tid] = ba1[tid];
        Wa2s[tid] = Wa2[tid];
        ts_s[tid] = INFINITY;
    }
    if (tid < 40) { bf1s[tid] = bf1[tid]; bf2s[tid] = bf2[tid]; }
    if (tid < 5)  { bf3s[tid] = bf3[tid]; }
    const float ba2v = ba2[0];
    __syncthreads();

    if (tid < HH) {      // rank sort
        float t = tts[tid];
        int r = 0;
        for (int i = 0; i < HH; ++i) {
            float ti = tts[i];
            r += (ti < t) || (ti == t && i < tid);
        }
        ts_s[r] = t;
        rnk[tid] = r;
    }
    __syncthreads();
    for (int idx = tid; idx < NIV * 32; idx += TPBB) {
        int r = idx >> 5, k = idx & 31;
        float a = 0.f, bb = 0.f;
        if (k < HH) {
            for (int j = 0; j < HH; ++j) {
                float w = w1s[j];
                bool act = (w > 0.f) ? (rnk[j] < r)
                         : ((w < 0.f) ? (rnk[j] >= r) : (b1s[j] > 0.f));
                if (act) {
                    float w2 = W2s[j][k];
                    a  = fmaf(w,      w2, a);
                    bb = fmaf(b1s[j], w2, bb);
                }
            }
            bb += b2s[k];
        }
        abt[r][k]      = a;
        abt[r][32 + k] = bb;
    }
    __syncthreads();
    for (int idx = tid; idx < NIV * 32; idx += TPBB) {
        int r = idx >> 5, m = idx & 31;
        float u = 0.f, v = 0.f;
        for (int k = 0; k < HH; ++k) {
            float wa = Wa1s[k][m];
            u = fmaf(wa, abt[r][k],      u);
            v = fmaf(wa, abt[r][32 + k], v);
        }
        v += ba1s[m];
        uvt[r][m]      = u;
        uvt[r][32 + m] = v;
    }
    __syncthreads();

    float sum[HH], ssq[HH], mx[HH], mn[HH], acc[HH];
    #pragma unroll
    for (int k = 0; k < HH; ++k) {
        sum[k] = 0.f; ssq[k] = 0.f; acc[k] = 0.f;
        mx[k] = -INFINITY; mn[k] = INFINITY;
    }
    float mrun = -INFINITY, lrun = 0.f;
    const float* xb = x + (size_t)b * NN;
    const float4* ts4 = (const float4*)ts_s;
    const float4* wv4 = (const float4*)Wa2s;

    #pragma unroll 1
    for (int it = 0; it < NN / TPBB; ++it) {
        float xv = xb[it * TPBB + tid];
        int r = 0;
        #pragma unroll
        for (int i = 0; i < 8; ++i) {
            float4 t = ts4[i];
            r += (xv >= t.x) ? 1 : 0;
            r += (xv >= t.y) ? 1 : 0;
            r += (xv >= t.z) ? 1 : 0;
            r += (xv >= t.w) ? 1 : 0;
        }
        float h2[HH];
        const float4* arow = (const float4*)(&abt[r][0]);
        #pragma unroll
        for (int i = 0; i < 7; ++i) {
            float4 av = arow[i], bv = arow[8 + i];
            h2[4*i+0] = fmaf(xv, av.x, bv.x);
            h2[4*i+1] = fmaf(xv, av.y, bv.y);
            h2[4*i+2] = fmaf(xv, av.z, bv.z);
            h2[4*i+3] = fmaf(xv, av.w, bv.w);
        }
        { float4 av = arow[7], bv = arow[15];
          h2[28] = fmaf(xv, av.x, bv.x);
          h2[29] = fmaf(xv, av.y, bv.y); }
        #pragma unroll
        for (int k = 0; k < HH; ++k) {
            float h = h2[k];
            sum[k] += h;
            ssq[k] = fmaf(h, h, ssq[k]);
            mx[k] = fmaxf(mx[k], h);
            mn[k] = fminf(mn[k], h);
        }
        float l = ba2v;
        const float4* urow = (const float4*)(&uvt[r][0]);
        #pragma unroll
        for (int i = 0; i < 8; ++i) {
            float4 uu = urow[i], vv = urow[8 + i], ww = wv4[i];
            l = fmaf(fmaxf(fmaf(xv, uu.x, vv.x), 0.f), ww.x, l);
            l = fmaf(fmaxf(fmaf(xv, uu.y, vv.y), 0.f), ww.y, l);
            l = fmaf(fmaxf(fmaf(xv, uu.z, vv.z), 0.f), ww.z, l);
            l = fmaf(fmaxf(fmaf(xv, uu.w, vv.w), 0.f), ww.w, l);
        }
        float d = l - mrun, p;
        if (d > 8.f) {
            float s = __expf(-d);
            lrun *= s;
            #pragma unroll
            for (int k = 0; k < HH; ++k) acc[k] *= s;
            mrun = l; p = 1.f;
        } else p = __expf(d);
        lrun += p;
        #pragma unroll
        for (int k = 0; k < HH; ++k) acc[k] = fmaf(p, h2[k], acc[k]);
    }

    #pragma unroll 1
    for (int off = 32; off > 0; off >>= 1) {
        #pragma unroll
        for (int k = 0; k < HH; ++k) {
            sum[k] += __shfl_xor(sum[k], off);
            ssq[k] += __shfl_xor(ssq[k], off);
            mx[k] = fmaxf(mx[k], __shfl_xor(mx[k], off));
            mn[k] = fminf(mn[k], __shfl_xor(mn[k], off));
        }
        float mo = __shfl_xor(mrun, off);
        float lo = __shfl_xor(lrun, off);
        float M  = fmaxf(mrun, mo);
        float sa = __expf(mrun - M), sb = __expf(mo - M);
        lrun = lrun * sa + lo * sb;
        #pragma unroll
        for (int k = 0; k < HH; ++k)
            acc[k] = acc[k] * sa + __shfl_xor(acc[k], off) * sb;
        mrun = M;
    }

    const int wave = tid >> 6, lane = tid & 63;
    if (lane == 0) {
        #pragma unroll
        for (int k = 0; k < HH; ++k) {
            red[wave][k]       = sum[k];
            red[wave][30 + k]  = ssq[k];
            red[wave][60 + k]  = mx[k];
            red[wave][90 + k]  = mn[k];
            red[wave][120 + k] = acc[k];
        }
        red[wave][150] = mrun;
        red[wave][151] = lrun;
    }
    __syncthreads();

    if (tid < HH) {
        float M = -INFINITY;
        #pragma unroll
        for (int w = 0; w < 8; ++w) M = fmaxf(M, red[w][150]);
        float s = 0.f, ss = 0.f, L = 0.f, A = 0.f;
        float mxv = -INFINITY, mnv = INFINITY;
        #pragma unroll
        for (int w = 0; w < 8; ++w) {
            s  += red[w][tid];
            ss += red[w][30 + tid];
            mxv = fmaxf(mxv, red[w][60 + tid]);
            mnv = fminf(mnv, red[w][90 + tid]);
            float e = __expf(red[w][150] - M);
            L = fmaf(red[w][151], e, L);
            A = fmaf(red[w][120 + tid], e, A);
        }
        const float invN = 1.f / (float)NN;
        float mean = s * invN;
        float var  = fmaxf(ss * invN - mean * mean, 0.f);
        feat[tid]       = mean;
        feat[30 + tid]  = mxv;
        feat[60 + tid]  = mnv;
        feat[90 + tid]  = sqrtf(var);
        feat[120 + tid] = s;
        feat[150 + tid] = A / L;
    }
    __syncthreads();

    if (tid < 480) {
        int o = tid % 40, p = tid / 40;
        float z = 0.f;
        #pragma unroll
        for (int ii = 0; ii < 15; ++ii)
            z = fmaf(feat[p * 15 + ii], wf1s[(p * 15 + ii) * 40 + o], z);
        redh[p][o] = z;
    }
    __syncthreads();
    if (tid < 40) {
        float z = bf1s[tid];
        #pragma unroll
        for (int p = 0; p < 12; ++p) z += redh[p][tid];
        z1s[tid] = fmaxf(z, 0.f);
    }
    __syncthreads();
    if (tid < 40) {
        float z = bf2s[tid];
        #pragma unroll
        for (int i = 0; i < 40; ++i) z = fmaf(z1s[i], wf2s[i * 40 + tid], z);
        z2s[tid] = fmaxf(z, 0.f);
    }
    __syncthreads();
    if (tid < 5) {
        float o = bf3s[tid];
        #pragma unroll
        for (int i = 0; i < 40; ++i) o = fmaf(z2s[i], wf3s[i * 5 + tid], o);
        out[b * 5 + tid] = o;
    }
}

extern "C" void kernel_launch(void* const* d_in, const int* in_sizes, int n_in,
                              void* d_out, int out_size, void* d_ws, size_t ws_size,
                              hipStream_t stream) {
    const float* x   = (const float*)d_in[0];
    const float* W1  = (const float*)d_in[1];
    const float* b1  = (const float*)d_in[2];
    const float* W2  = (const float*)d_in[3];
    const float* b2  = (const float*)d_in[4];
    const float* Wa1 = (const float*)d_in[5];
    const float* ba1 = (const float*)d_in[6];
    const float* Wa2 = (const float*)d_in[7];
    const float* ba2 = (const float*)d_in[8];
    const float* Wf1 = (const float*)d_in[9];
    const float* bf1 = (const float*)d_in[10];
    const float* Wf2 = (const float*)d_in[11];
    const float* bf2 = (const float*)d_in[12];
    const float* Wf3 = (const float*)d_in[13];
    const float* bf3 = (const float*)d_in[14];
    float* out = (float*)d_out;
    int* wsflag = (int*)d_ws;

    pointnet_fastA<<<256, TPBA, 0, stream>>>(
        x, W1, b1, W2, b2, Wa1, ba1, Wa2, ba2,
        Wf1, bf1, Wf2, bf2, Wf3, bf3, out, wsflag);
    pointnet_fbB<<<256, TPBB, 0, stream>>>(
        x, W1, b1, W2, b2, Wa1, ba1, Wa2, ba2,
        Wf1, bf1, Wf2, bf2, Wf3, bf3, out, wsflag);
}